// Round 2
// baseline (8319.515 us; speedup 1.0000x reference)
//
#include <hip/hip_runtime.h>

#define DEVINL __device__ __forceinline__

DEVINL float leakyf(float v) { return v > 0.f ? v : 0.2f * v; }
DEVINL float eluf(float v)   { return v > 0.f ? v : __expf(v) - 1.f; }

// Zero-fill (replaces hipMemsetAsync; plain stream kernel, graph-safe).
__global__ void __launch_bounds__(256) k_zero(float* __restrict__ p, int total) {
  int t = blockIdx.x * blockDim.x + threadIdx.x;
  if (t < total) p[t] = 0.f;
}

// ---------------------------------------------------------------------------
// K_prep: fold attention vectors into input space.
// wa1s[h][c] = sum_d W1[(h*32+d)*23 + c] * a_src1[h*32+d]   (4x23)
// wa2s[h][c] = sum_d W2[(h*32+d)*128 + c] * a_src2[h*32+d]  (4x128)
// ---------------------------------------------------------------------------
__global__ void k_prep(const float* __restrict__ W1, const float* __restrict__ as1,
                       const float* __restrict__ ad1,
                       const float* __restrict__ W2, const float* __restrict__ as2,
                       const float* __restrict__ ad2,
                       float* __restrict__ wa1s, float* __restrict__ wa1d,
                       float* __restrict__ wa2s, float* __restrict__ wa2d) {
  int t = threadIdx.x;  // 512 threads
  if (t < 92) {
    int h = t / 23, c = t % 23;
    float s1 = 0.f, s2 = 0.f;
    for (int dd = 0; dd < 32; ++dd) {
      float w = W1[(h * 32 + dd) * 23 + c];
      s1 += w * as1[h * 32 + dd];
      s2 += w * ad1[h * 32 + dd];
    }
    wa1s[t] = s1;
    wa1d[t] = s2;
  }
  {
    int h = t >> 7, c = t & 127;
    float s1 = 0.f, s2 = 0.f;
    for (int dd = 0; dd < 32; ++dd) {
      float w = W2[(h * 32 + dd) * 128 + c];
      s1 += w * as2[h * 32 + dd];
      s2 += w * ad2[h * 32 + dd];
    }
    wa2s[t] = s1;
    wa2d[t] = s2;
  }
}

// ---------------------------------------------------------------------------
// K_g1: g1[n,k] = h_n . W1[k,:]  (h_n = [x[n,:12], u[:11]], 23 long)
// plus per-node attention logits via folded wa vectors.
// One block (128 threads) per node.
// ---------------------------------------------------------------------------
__global__ void __launch_bounds__(128) k_g1(
    const float* __restrict__ x, const float* __restrict__ u,
    const float* __restrict__ W1,
    const float* __restrict__ wa1s, const float* __restrict__ wa1d,
    float* __restrict__ g1, float* __restrict__ al1s, float* __restrict__ al1d) {
  int n = blockIdx.x, k = threadIdx.x;
  __shared__ float hs[23];
  if (k < 12) hs[k] = x[n * 12 + k];
  else if (k < 23) hs[k] = u[k - 12];
  __syncthreads();
  const float* w = W1 + k * 23;
  float s = 0.f;
#pragma unroll
  for (int c = 0; c < 23; ++c) s += hs[c] * w[c];
  g1[n * 128 + k] = s;
  if (k < 8) {
    int h = k & 3;
    const float* wa = (k < 4 ? wa1s : wa1d) + h * 23;
    float t = 0.f;
#pragma unroll
    for (int c = 0; c < 23; ++c) t += hs[c] * wa[c];
    (k < 4 ? al1s : al1d)[n * 4 + h] = t;
  }
}

// ---------------------------------------------------------------------------
// K_att: per edge (incl. self-loops e>=M), denom[dst,h] += exp(leaky(logit)).
// segment_max skipped: logits are O(+-1) here (softmax shift-invariant).
// ---------------------------------------------------------------------------
__global__ void __launch_bounds__(256) k_att(
    const float* __restrict__ als, const float* __restrict__ ald,
    const int* __restrict__ ei, float* __restrict__ den, int M, int E) {
  int e = blockIdx.x * blockDim.x + threadIdx.x;
  if (e >= E) return;
  int s, d;
  if (e < M) { s = ei[e]; d = ei[M + e]; } else { s = e - M; d = s; }
  const float4 as = *(const float4*)(als + s * 4);
  const float4 ad = *(const float4*)(ald + d * 4);
  unsafeAtomicAdd(&den[d * 4 + 0], __expf(leakyf(as.x + ad.x)));
  unsafeAtomicAdd(&den[d * 4 + 1], __expf(leakyf(as.y + ad.y)));
  unsafeAtomicAdd(&den[d * 4 + 2], __expf(leakyf(as.z + ad.z)));
  unsafeAtomicAdd(&den[d * 4 + 3], __expf(leakyf(as.w + ad.w)));
}

// ---------------------------------------------------------------------------
// K_sc: scatter messages. thread = (edge, q) with q<32 covering dims 4q..4q+3.
// acc[dst, k] += alpha[e, k/32] * g[src, k]
// ---------------------------------------------------------------------------
__global__ void __launch_bounds__(256) k_sc(
    const float* __restrict__ g, const float* __restrict__ als,
    const float* __restrict__ ald, const float* __restrict__ den,
    const int* __restrict__ ei, float* __restrict__ acc, int M, int E) {
  int t = blockIdx.x * blockDim.x + threadIdx.x;
  if (t >= E * 32) return;
  int e = t >> 5, q = t & 31;
  int s, d;
  if (e < M) { s = ei[e]; d = ei[M + e]; } else { s = e - M; d = s; }
  int h = q >> 3;
  float lv = als[s * 4 + h] + ald[d * 4 + h];
  float alpha = __expf(leakyf(lv)) / den[d * 4 + h];
  float4 gv = *(const float4*)(g + s * 128 + q * 4);
  float* o = acc + d * 128 + q * 4;
  unsafeAtomicAdd(o + 0, gv.x * alpha);
  unsafeAtomicAdd(o + 1, gv.y * alpha);
  unsafeAtomicAdd(o + 2, gv.z * alpha);
  unsafeAtomicAdd(o + 3, gv.w * alpha);
}

// K_fin1: h2 = elu(acc1 + b1), in place.
__global__ void __launch_bounds__(256) k_fin1(
    float* __restrict__ acc, const float* __restrict__ b1, int total) {
  int t = blockIdx.x * blockDim.x + threadIdx.x;
  if (t >= total) return;
  acc[t] = eluf(acc[t] + b1[t & 127]);
}

// K_g2: g2[n,k] = h2[n,:] . W2[k,:], dot-128 via float4.
__global__ void __launch_bounds__(256) k_g2(
    const float* __restrict__ h2, const float* __restrict__ W2,
    float* __restrict__ g2, int total) {
  int t = blockIdx.x * blockDim.x + threadIdx.x;
  if (t >= total) return;
  int n = t >> 7, k = t & 127;
  const float4* hr = (const float4*)(h2 + n * 128);
  const float4* wr = (const float4*)(W2 + k * 128);
  float s = 0.f;
#pragma unroll
  for (int i = 0; i < 32; ++i) {
    float4 a = hr[i], b = wr[i];
    s += a.x * b.x + a.y * b.y + a.z * b.z + a.w * b.w;
  }
  g2[t] = s;
}

// K_al2: al2{s,d}[n,h] = h2[n,:] . wa2{s,d}[h,:]
__global__ void __launch_bounds__(256) k_al2(
    const float* __restrict__ h2, const float* __restrict__ wa2s,
    const float* __restrict__ wa2d, float* __restrict__ al2s,
    float* __restrict__ al2d, int total) {
  int t = blockIdx.x * blockDim.x + threadIdx.x;
  if (t >= total) return;
  int n = t >> 3, j = t & 7, h = j & 3;
  const float4* hr = (const float4*)(h2 + n * 128);
  const float4* wr = (const float4*)((j < 4 ? wa2s : wa2d) + h * 128);
  float s = 0.f;
#pragma unroll
  for (int i = 0; i < 32; ++i) {
    float4 a = hr[i], b = wr[i];
    s += a.x * b.x + a.y * b.y + a.z * b.z + a.w * b.w;
  }
  (j < 4 ? al2s : al2d)[n * 4 + h] = s;
}

// K_fin2: h3 = elu(mean_over_heads(acc2) + b2)  -> [N,32]
__global__ void __launch_bounds__(256) k_fin2(
    const float* __restrict__ acc, const float* __restrict__ b2,
    float* __restrict__ h3, int total) {
  int t = blockIdx.x * blockDim.x + threadIdx.x;
  if (t >= total) return;
  int n = t >> 5, dl = t & 31;
  const float* a = acc + n * 128 + dl;
  float v = 0.25f * (a[0] + a[32] + a[64] + a[96]) + b2[dl];
  h3[t] = eluf(v);
}

// ---------------------------------------------------------------------------
// K_dec: per-edge MLP 69->64->32->4. Weights are wave-uniform -> scalar loads;
// all activations in registers (fully static indexing).
// ---------------------------------------------------------------------------
__global__ void __launch_bounds__(256) k_dec(
    const float* __restrict__ h3, const int* __restrict__ ei,
    const float* __restrict__ ea,
    const float* __restrict__ dw1, const float* __restrict__ db1,
    const float* __restrict__ dw2, const float* __restrict__ db2,
    const float* __restrict__ dw3, const float* __restrict__ db3,
    float* __restrict__ out, int M) {
  int m = blockIdx.x * blockDim.x + threadIdx.x;
  if (m >= M) return;
  int s = ei[m], d = ei[M + m];
  float ein[69];
  const float4* hs4 = (const float4*)(h3 + s * 32);
  const float4* hd4 = (const float4*)(h3 + d * 32);
#pragma unroll
  for (int i = 0; i < 8; ++i) {
    float4 v = hs4[i];
    ein[i * 4 + 0] = v.x; ein[i * 4 + 1] = v.y;
    ein[i * 4 + 2] = v.z; ein[i * 4 + 3] = v.w;
    float4 w = hd4[i];
    ein[32 + i * 4 + 0] = w.x; ein[32 + i * 4 + 1] = w.y;
    ein[32 + i * 4 + 2] = w.z; ein[32 + i * 4 + 3] = w.w;
  }
#pragma unroll
  for (int j = 0; j < 5; ++j) ein[64 + j] = ea[m * 5 + j];

  float z1[64];
#pragma unroll
  for (int k = 0; k < 64; ++k) {
    float acc = db1[k];
    const float* w = dw1 + k * 69;
#pragma unroll
    for (int c = 0; c < 69; ++c) acc += ein[c] * w[c];
    z1[k] = fmaxf(acc, 0.f);
  }
  float z2[32];
#pragma unroll
  for (int k = 0; k < 32; ++k) {
    float acc = db2[k];
    const float* w = dw2 + k * 64;
#pragma unroll
    for (int c = 0; c < 64; ++c) acc += z1[c] * w[c];
    z2[k] = fmaxf(acc, 0.f);
  }
  float o0 = db3[0], o1 = db3[1], o2 = db3[2], o3 = db3[3];
#pragma unroll
  for (int c = 0; c < 32; ++c) {
    float z = z2[c];
    o0 += z * dw3[c];
    o1 += z * dw3[32 + c];
    o2 += z * dw3[64 + c];
    o3 += z * dw3[96 + c];
  }
  float4 o = make_float4(o0, o1, o2, o3);
  *(float4*)(out + m * 4) = o;
}

// ---------------------------------------------------------------------------
extern "C" void kernel_launch(void* const* d_in, const int* in_sizes, int n_in,
                              void* d_out, int out_size, void* d_ws, size_t ws_size,
                              hipStream_t stream) {
  const float* x   = (const float*)d_in[0];
  const int*   ei  = (const int*)d_in[1];
  const float* ea  = (const float*)d_in[2];
  const float* u   = (const float*)d_in[3];
  const float* W1  = (const float*)d_in[4];
  const float* as1 = (const float*)d_in[5];
  const float* ad1 = (const float*)d_in[6];
  const float* b1  = (const float*)d_in[7];
  const float* W2  = (const float*)d_in[8];
  const float* as2 = (const float*)d_in[9];
  const float* ad2 = (const float*)d_in[10];
  const float* b2  = (const float*)d_in[11];
  const float* dw1 = (const float*)d_in[12];
  const float* db1 = (const float*)d_in[13];
  const float* dw2 = (const float*)d_in[14];
  const float* db2 = (const float*)d_in[15];
  const float* dw3 = (const float*)d_in[16];
  const float* db3 = (const float*)d_in[17];
  float* out = (float*)d_out;

  const int N = in_sizes[0] / 12;
  const int M = in_sizes[1] / 2;
  const int E = M + N;

  float* ws = (float*)d_ws;
  float* A    = ws;                      // N*128: g1, then g2
  float* B    = A + (size_t)N * 128;     // N*128: acc1 -> h2 (in place) -> acc2
  float* DEN1 = B + (size_t)N * 128;     // N*4  (contiguous with B for one zero pass)
  float* DEN2 = DEN1 + (size_t)N * 4;    // N*4
  float* H3   = DEN2 + (size_t)N * 4;    // N*32
  float* AL1S = H3 + (size_t)N * 32;     // N*4 each below
  float* AL1D = AL1S + (size_t)N * 4;
  float* AL2S = AL1D + (size_t)N * 4;
  float* AL2D = AL2S + (size_t)N * 4;
  float* WA1S = AL2D + (size_t)N * 4;    // 96 (4x23 padded)
  float* WA1D = WA1S + 96;
  float* WA2S = WA1D + 96;               // 512 (4x128)
  float* WA2D = WA2S + 512;

  // zero B + DEN1 + DEN2 in one pass (contiguous)
  int z0 = N * 136;
  k_zero<<<(z0 + 255) / 256, 256, 0, stream>>>(B, z0);

  k_prep<<<1, 512, 0, stream>>>(W1, as1, ad1, W2, as2, ad2, WA1S, WA1D, WA2S, WA2D);

  // --- conv1 ---
  k_g1<<<N, 128, 0, stream>>>(x, u, W1, WA1S, WA1D, A, AL1S, AL1D);
  int gE = (E + 255) / 256;
  k_att<<<gE, 256, 0, stream>>>(AL1S, AL1D, ei, DEN1, M, E);
  int gS = (int)(((long long)E * 32 + 255) / 256);
  k_sc<<<gS, 256, 0, stream>>>(A, AL1S, AL1D, DEN1, ei, B, M, E);
  k_fin1<<<(N * 128 + 255) / 256, 256, 0, stream>>>(B, b1, N * 128);

  // --- conv2 ---
  k_g2<<<(N * 128 + 255) / 256, 256, 0, stream>>>(B, W2, A, N * 128);
  k_al2<<<(N * 8 + 255) / 256, 256, 0, stream>>>(B, WA2S, WA2D, AL2S, AL2D, N * 8);
  k_zero<<<(N * 128 + 255) / 256, 256, 0, stream>>>(B, N * 128);  // acc2
  k_att<<<gE, 256, 0, stream>>>(AL2S, AL2D, ei, DEN2, M, E);
  k_sc<<<gS, 256, 0, stream>>>(A, AL2S, AL2D, DEN2, ei, B, M, E);
  k_fin2<<<(N * 32 + 255) / 256, 256, 0, stream>>>(B, b2, H3, N * 32);

  // --- decoder ---
  k_dec<<<(M + 255) / 256, 256, 0, stream>>>(H3, ei, ea, dw1, db1, dw2, db2,
                                             dw3, db3, out, M);
}

// Round 3
// 2257.845 us; speedup vs baseline: 3.6847x; 3.6847x over previous
//
#include <hip/hip_runtime.h>

#define DEVINL __device__ __forceinline__

DEVINL float leakyf(float v) { return v > 0.f ? v : 0.2f * v; }
DEVINL float eluf(float v)   { return v > 0.f ? v : __expf(v) - 1.f; }

// ---------------------------------------------------------------------------
// int zero fill
// ---------------------------------------------------------------------------
__global__ void __launch_bounds__(256) k_izero(int* __restrict__ p, int total) {
  int t = blockIdx.x * blockDim.x + threadIdx.x;
  if (t < total) p[t] = 0;
}

// ---------------------------------------------------------------------------
// CSR build: count incoming edges per dst (self-loops appended, e >= M).
// ---------------------------------------------------------------------------
__global__ void __launch_bounds__(256) k_count(const int* __restrict__ ei,
                                               int* __restrict__ cnt, int M, int E) {
  int e = blockIdx.x * blockDim.x + threadIdx.x;
  if (e >= E) return;
  int d = (e < M) ? ei[M + e] : e - M;
  atomicAdd(&cnt[d], 1);
}

// Per-256-block exclusive scan; block totals to bsum.
__global__ void __launch_bounds__(256) k_scan1(const int* __restrict__ cnt,
                                               int* __restrict__ off,
                                               int* __restrict__ bsum, int N) {
  __shared__ int sh[256];
  int i = blockIdx.x * 256 + threadIdx.x;
  int v = (i < N) ? cnt[i] : 0;
  sh[threadIdx.x] = v;
  __syncthreads();
  for (int o = 1; o < 256; o <<= 1) {
    int t = (threadIdx.x >= o) ? sh[threadIdx.x - o] : 0;
    __syncthreads();
    sh[threadIdx.x] += t;
    __syncthreads();
  }
  if (i < N) off[i] = sh[threadIdx.x] - v;  // exclusive within block
  if (threadIdx.x == 255) bsum[blockIdx.x] = sh[255];
}

// Exclusive scan of block sums (nb <= 512), one block of 512.
__global__ void __launch_bounds__(512) k_scan2(int* __restrict__ bsum, int nb) {
  __shared__ int sh[512];
  int t = threadIdx.x;
  int v = (t < nb) ? bsum[t] : 0;
  sh[t] = v;
  __syncthreads();
  for (int o = 1; o < 512; o <<= 1) {
    int x = (t >= o) ? sh[t - o] : 0;
    __syncthreads();
    sh[t] += x;
    __syncthreads();
  }
  if (t < nb) bsum[t] = sh[t] - v;
}

// Add block bases; zero cursors; set off[N] = E.
__global__ void __launch_bounds__(256) k_scan3(int* __restrict__ off,
                                               const int* __restrict__ bsum,
                                               int* __restrict__ cur, int N, int E) {
  int i = blockIdx.x * 256 + threadIdx.x;
  if (i < N) { off[i] += bsum[i >> 8]; cur[i] = 0; }
  if (i == N) off[N] = E;
}

// Place src of each edge into its dst's CSR segment.
__global__ void __launch_bounds__(256) k_fill(const int* __restrict__ ei,
                                              const int* __restrict__ off,
                                              int* __restrict__ cur,
                                              int* __restrict__ ssrc, int M, int E) {
  int e = blockIdx.x * blockDim.x + threadIdx.x;
  if (e >= E) return;
  int s, d;
  if (e < M) { s = ei[e]; d = ei[M + e]; } else { s = e - M; d = s; }
  int pos = off[d] + atomicAdd(&cur[d], 1);
  ssrc[pos] = s;
}

// ---------------------------------------------------------------------------
// K_prep: fold attention vectors into input space.
// ---------------------------------------------------------------------------
__global__ void k_prep(const float* __restrict__ W1, const float* __restrict__ as1,
                       const float* __restrict__ ad1,
                       const float* __restrict__ W2, const float* __restrict__ as2,
                       const float* __restrict__ ad2,
                       float* __restrict__ wa1s, float* __restrict__ wa1d,
                       float* __restrict__ wa2s, float* __restrict__ wa2d) {
  int t = threadIdx.x;  // 512 threads
  if (t < 92) {
    int h = t / 23, c = t % 23;
    float s1 = 0.f, s2 = 0.f;
    for (int dd = 0; dd < 32; ++dd) {
      float w = W1[(h * 32 + dd) * 23 + c];
      s1 += w * as1[h * 32 + dd];
      s2 += w * ad1[h * 32 + dd];
    }
    wa1s[t] = s1;
    wa1d[t] = s2;
  }
  {
    int h = t >> 7, c = t & 127;
    float s1 = 0.f, s2 = 0.f;
    for (int dd = 0; dd < 32; ++dd) {
      float w = W2[(h * 32 + dd) * 128 + c];
      s1 += w * as2[h * 32 + dd];
      s2 += w * ad2[h * 32 + dd];
    }
    wa2s[t] = s1;
    wa2d[t] = s2;
  }
}

// ---------------------------------------------------------------------------
// K_g1: g1[n,k] = h_n . W1[k,:], plus folded attention logits.
// ---------------------------------------------------------------------------
__global__ void __launch_bounds__(128) k_g1(
    const float* __restrict__ x, const float* __restrict__ u,
    const float* __restrict__ W1,
    const float* __restrict__ wa1s, const float* __restrict__ wa1d,
    float* __restrict__ g1, float* __restrict__ al1s, float* __restrict__ al1d) {
  int n = blockIdx.x, k = threadIdx.x;
  __shared__ float hs[23];
  if (k < 12) hs[k] = x[n * 12 + k];
  else if (k < 23) hs[k] = u[k - 12];
  __syncthreads();
  const float* w = W1 + k * 23;
  float s = 0.f;
#pragma unroll
  for (int c = 0; c < 23; ++c) s += hs[c] * w[c];
  g1[n * 128 + k] = s;
  if (k < 8) {
    int h = k & 3;
    const float* wa = (k < 4 ? wa1s : wa1d) + h * 23;
    float t = 0.f;
#pragma unroll
    for (int c = 0; c < 23; ++c) t += hs[c] * wa[c];
    (k < 4 ? al1s : al1d)[n * 4 + h] = t;
  }
}

// ---------------------------------------------------------------------------
// K_gat: fused attention + softmax + aggregate per dst node via CSR gather.
// out = sum_e w_e * g[src_e] / sum_e w_e,  w_e = exp(leaky(als[s]+ald[d])).
// MODE 0: out128 = elu(v + b1[k])   (concat heads)
// MODE 1: out32  = elu(mean_heads(v) + b2[k&31])
// One block of 128 threads per dst node; lane k covers channel k, head k>>5.
// ---------------------------------------------------------------------------
template <int MODE>
__global__ void __launch_bounds__(128) k_gat(
    const float* __restrict__ g, const float* __restrict__ als,
    const float* __restrict__ ald, const int* __restrict__ off,
    const int* __restrict__ ssrc, const float* __restrict__ bias,
    float* __restrict__ outp) {
  int d = blockIdx.x, t = threadIdx.x, h = t >> 5;
  float av = ald[d * 4 + h];
  int p0 = off[d], p1 = off[d + 1];
  float acc = 0.f, den = 0.f;
  int sA = ssrc[p0];  // deg >= 1 (self-loop)
  for (int p = p0; p < p1;) {
    int s = sA;
    int pn = p + 1;
    if (pn < p1) sA = ssrc[pn];
    float w = __expf(leakyf(als[s * 4 + h] + av));
    acc += w * g[(size_t)s * 128 + t];
    den += w;
    p = pn;
  }
  float v = acc / den;
  if (MODE == 0) {
    outp[(size_t)d * 128 + t] = eluf(v + bias[t]);
  } else {
    __shared__ float sh[128];
    sh[t] = v;
    __syncthreads();
    if (t < 32) {
      float m = 0.25f * (sh[t] + sh[t + 32] + sh[t + 64] + sh[t + 96]);
      outp[(size_t)d * 32 + t] = eluf(m + bias[t]);
    }
  }
}

// K_g2: g2[n,k] = h2[n,:] . W2[k,:], dot-128 via float4.
__global__ void __launch_bounds__(256) k_g2(
    const float* __restrict__ h2, const float* __restrict__ W2,
    float* __restrict__ g2, int total) {
  int t = blockIdx.x * blockDim.x + threadIdx.x;
  if (t >= total) return;
  int n = t >> 7, k = t & 127;
  const float4* hr = (const float4*)(h2 + (size_t)n * 128);
  const float4* wr = (const float4*)(W2 + k * 128);
  float s = 0.f;
#pragma unroll
  for (int i = 0; i < 32; ++i) {
    float4 a = hr[i], b = wr[i];
    s += a.x * b.x + a.y * b.y + a.z * b.z + a.w * b.w;
  }
  g2[t] = s;
}

// K_al2: al2{s,d}[n,h] = h2[n,:] . wa2{s,d}[h,:]
__global__ void __launch_bounds__(256) k_al2(
    const float* __restrict__ h2, const float* __restrict__ wa2s,
    const float* __restrict__ wa2d, float* __restrict__ al2s,
    float* __restrict__ al2d, int total) {
  int t = blockIdx.x * blockDim.x + threadIdx.x;
  if (t >= total) return;
  int n = t >> 3, j = t & 7, h = j & 3;
  const float4* hr = (const float4*)(h2 + (size_t)n * 128);
  const float4* wr = (const float4*)((j < 4 ? wa2s : wa2d) + h * 128);
  float s = 0.f;
#pragma unroll
  for (int i = 0; i < 32; ++i) {
    float4 a = hr[i], b = wr[i];
    s += a.x * b.x + a.y * b.y + a.z * b.z + a.w * b.w;
  }
  (j < 4 ? al2s : al2d)[n * 4 + h] = s;
}

// ---------------------------------------------------------------------------
// K_dec: per-edge MLP 69->64->32->4. Weights staged in LDS (broadcast reads);
// activations in registers, phase-structured to cap pressure (~120 VGPR):
//   phase A: 32 src feats (8 float4) x z1[64]
//   phase B: 32 dst feats            x z1[64]
//   phase C: 5 edge attrs            x z1[64]
// ---------------------------------------------------------------------------
__global__ void __launch_bounds__(256) k_dec(
    const float* __restrict__ h3, const int* __restrict__ ei,
    const float* __restrict__ ea,
    const float* __restrict__ dw1, const float* __restrict__ db1,
    const float* __restrict__ dw2, const float* __restrict__ db2,
    const float* __restrict__ dw3, const float* __restrict__ db3,
    float* __restrict__ out, int M) {
  __shared__ float w1s[64 * 72];  // [k][c], c padded 69->72 (16B-aligned rows)
  __shared__ float w2s[32 * 64];
  __shared__ float w3s[4 * 32];
  __shared__ float bbs[104];
  int t = threadIdx.x;
  for (int i = t; i < 64 * 72; i += 256) {
    int k = i / 72, c = i - k * 72;
    w1s[i] = (c < 69) ? dw1[k * 69 + c] : 0.f;
  }
  for (int i = t; i < 32 * 64; i += 256) w2s[i] = dw2[i];
  if (t < 128) w3s[t] = dw3[t];
  if (t < 64) bbs[t] = db1[t];
  else if (t < 96) bbs[t] = db2[t - 64];
  else if (t < 100) bbs[t] = db3[t - 96];
  __syncthreads();

  int m = blockIdx.x * 256 + t;
  if (m >= M) return;
  int s = ei[m], d = ei[M + m];

  float z1[64];
#pragma unroll
  for (int k = 0; k < 64; ++k) z1[k] = bbs[k];

  // phase A: src features (cols 0..31)
  {
    const float4* hp = (const float4*)(h3 + (size_t)s * 32);
    float4 q[8];
#pragma unroll
    for (int i = 0; i < 8; ++i) q[i] = hp[i];
#pragma unroll
    for (int cq = 0; cq < 8; ++cq) {
      float4 e = q[cq];
#pragma unroll
      for (int k = 0; k < 64; ++k) {
        float4 w = *(const float4*)(w1s + k * 72 + cq * 4);
        z1[k] += e.x * w.x + e.y * w.y + e.z * w.z + e.w * w.w;
      }
    }
  }
  // phase B: dst features (cols 32..63)
  {
    const float4* hp = (const float4*)(h3 + (size_t)d * 32);
    float4 q[8];
#pragma unroll
    for (int i = 0; i < 8; ++i) q[i] = hp[i];
#pragma unroll
    for (int cq = 0; cq < 8; ++cq) {
      float4 e = q[cq];
#pragma unroll
      for (int k = 0; k < 64; ++k) {
        float4 w = *(const float4*)(w1s + k * 72 + 32 + cq * 4);
        z1[k] += e.x * w.x + e.y * w.y + e.z * w.z + e.w * w.w;
      }
    }
  }
  // phase C: edge attrs (cols 64..68)
  {
    const float* ep = ea + (size_t)m * 5;
    float4 e = make_float4(ep[0], ep[1], ep[2], ep[3]);
    float e4 = ep[4];
#pragma unroll
    for (int k = 0; k < 64; ++k) {
      float4 w = *(const float4*)(w1s + k * 72 + 64);
      z1[k] += e.x * w.x + e.y * w.y + e.z * w.z + e.w * w.w +
               e4 * w1s[k * 72 + 68];
    }
  }
#pragma unroll
  for (int k = 0; k < 64; ++k) z1[k] = fmaxf(z1[k], 0.f);

  // layer 2: 64 -> 32
  float z2[32];
#pragma unroll
  for (int k = 0; k < 32; ++k) z2[k] = bbs[64 + k];
#pragma unroll
  for (int cq = 0; cq < 16; ++cq) {
    float4 e = make_float4(z1[cq * 4], z1[cq * 4 + 1], z1[cq * 4 + 2],
                           z1[cq * 4 + 3]);
#pragma unroll
    for (int k = 0; k < 32; ++k) {
      float4 w = *(const float4*)(w2s + k * 64 + cq * 4);
      z2[k] += e.x * w.x + e.y * w.y + e.z * w.z + e.w * w.w;
    }
  }
#pragma unroll
  for (int k = 0; k < 32; ++k) z2[k] = fmaxf(z2[k], 0.f);

  // layer 3: 32 -> 4
  float o0 = bbs[96], o1 = bbs[97], o2 = bbs[98], o3 = bbs[99];
#pragma unroll
  for (int cq = 0; cq < 8; ++cq) {
    float4 e = make_float4(z2[cq * 4], z2[cq * 4 + 1], z2[cq * 4 + 2],
                           z2[cq * 4 + 3]);
    float4 wa = *(const float4*)(w3s + 0 * 32 + cq * 4);
    float4 wb = *(const float4*)(w3s + 1 * 32 + cq * 4);
    float4 wc = *(const float4*)(w3s + 2 * 32 + cq * 4);
    float4 wd = *(const float4*)(w3s + 3 * 32 + cq * 4);
    o0 += e.x * wa.x + e.y * wa.y + e.z * wa.z + e.w * wa.w;
    o1 += e.x * wb.x + e.y * wb.y + e.z * wb.z + e.w * wb.w;
    o2 += e.x * wc.x + e.y * wc.y + e.z * wc.z + e.w * wc.w;
    o3 += e.x * wd.x + e.y * wd.y + e.z * wd.z + e.w * wd.w;
  }
  *(float4*)(out + (size_t)m * 4) = make_float4(o0, o1, o2, o3);
}

// ---------------------------------------------------------------------------
extern "C" void kernel_launch(void* const* d_in, const int* in_sizes, int n_in,
                              void* d_out, int out_size, void* d_ws, size_t ws_size,
                              hipStream_t stream) {
  const float* x   = (const float*)d_in[0];
  const int*   ei  = (const int*)d_in[1];
  const float* ea  = (const float*)d_in[2];
  const float* u   = (const float*)d_in[3];
  const float* W1  = (const float*)d_in[4];
  const float* as1 = (const float*)d_in[5];
  const float* ad1 = (const float*)d_in[6];
  const float* b1  = (const float*)d_in[7];
  const float* W2  = (const float*)d_in[8];
  const float* as2 = (const float*)d_in[9];
  const float* ad2 = (const float*)d_in[10];
  const float* b2  = (const float*)d_in[11];
  const float* dw1 = (const float*)d_in[12];
  const float* db1 = (const float*)d_in[13];
  const float* dw2 = (const float*)d_in[14];
  const float* db2 = (const float*)d_in[15];
  const float* dw3 = (const float*)d_in[16];
  const float* db3 = (const float*)d_in[17];
  float* out = (float*)d_out;

  const int N = in_sizes[0] / 12;
  const int M = in_sizes[1] / 2;
  const int E = M + N;

  float* ws = (float*)d_ws;
  float* A    = ws;                      // N*128: g1, then g2
  float* B    = A + (size_t)N * 128;     // N*128: h2 (conv1 output, fused epilogue)
  float* H3   = B + (size_t)N * 128;     // N*32
  float* AL1S = H3 + (size_t)N * 32;     // N*4 each below
  float* AL1D = AL1S + (size_t)N * 4;
  float* AL2S = AL1D + (size_t)N * 4;
  float* AL2D = AL2S + (size_t)N * 4;
  float* WA1S = AL2D + (size_t)N * 4;    // 96 (4x23 padded)
  float* WA1D = WA1S + 96;
  float* WA2S = WA1D + 96;               // 512 (4x128)
  float* WA2D = WA2S + 512;
  // int region
  int* IOFF = (int*)(WA2D + 512);        // N+1
  int* ICUR = IOFF + (N + 1);            // N (counts, then cursors)
  int* IBS  = ICUR + N;                  // 512 block sums
  int* ISRC = IBS + 512;                 // E sorted srcs

  int nb = (N + 255) / 256;
  int gE = (E + 255) / 256;

  // --- CSR build (once, reused by both convs) ---
  k_izero<<<nb, 256, 0, stream>>>(ICUR, N);
  k_count<<<gE, 256, 0, stream>>>(ei, ICUR, M, E);
  k_scan1<<<nb, 256, 0, stream>>>(ICUR, IOFF, IBS, N);
  k_scan2<<<1, 512, 0, stream>>>(IBS, nb);
  k_scan3<<<(N + 256) / 256, 256, 0, stream>>>(IOFF, IBS, ICUR, N, E);
  k_fill<<<gE, 256, 0, stream>>>(ei, IOFF, ICUR, ISRC, M, E);

  k_prep<<<1, 512, 0, stream>>>(W1, as1, ad1, W2, as2, ad2, WA1S, WA1D, WA2S, WA2D);

  // --- conv1 ---
  k_g1<<<N, 128, 0, stream>>>(x, u, W1, WA1S, WA1D, A, AL1S, AL1D);
  k_gat<0><<<N, 128, 0, stream>>>(A, AL1S, AL1D, IOFF, ISRC, b1, B);

  // --- conv2 ---
  k_g2<<<(N * 128 + 255) / 256, 256, 0, stream>>>(B, W2, A, N * 128);
  k_al2<<<(N * 8 + 255) / 256, 256, 0, stream>>>(B, WA2S, WA2D, AL2S, AL2D, N * 8);
  k_gat<1><<<N, 128, 0, stream>>>(A, AL2S, AL2D, IOFF, ISRC, b2, H3);

  // --- decoder ---
  k_dec<<<(M + 255) / 256, 256, 0, stream>>>(H3, ei, ea, dw1, db1, dw2, db2,
                                             dw3, db3, out, M);
}

// Round 4
// 1497.415 us; speedup vs baseline: 5.5559x; 1.5078x over previous
//
#include <hip/hip_runtime.h>

#define DEVINL __device__ __forceinline__

DEVINL float leakyf(float v) { return v > 0.f ? v : 0.2f * v; }
DEVINL float eluf(float v)   { return v > 0.f ? v : __expf(v) - 1.f; }

// ---------------------------------------------------------------------------
// int zero fill
// ---------------------------------------------------------------------------
__global__ void __launch_bounds__(256) k_izero(int* __restrict__ p, int total) {
  int t = blockIdx.x * blockDim.x + threadIdx.x;
  if (t < total) p[t] = 0;
}

// ---------------------------------------------------------------------------
// CSR build: count incoming edges per dst (self-loops appended, e >= M).
// ---------------------------------------------------------------------------
__global__ void __launch_bounds__(256) k_count(const int* __restrict__ ei,
                                               int* __restrict__ cnt, int M, int E) {
  int e = blockIdx.x * blockDim.x + threadIdx.x;
  if (e >= E) return;
  int d = (e < M) ? ei[M + e] : e - M;
  atomicAdd(&cnt[d], 1);
}

// Per-256-block exclusive scan; block totals to bsum.
__global__ void __launch_bounds__(256) k_scan1(const int* __restrict__ cnt,
                                               int* __restrict__ off,
                                               int* __restrict__ bsum, int N) {
  __shared__ int sh[256];
  int i = blockIdx.x * 256 + threadIdx.x;
  int v = (i < N) ? cnt[i] : 0;
  sh[threadIdx.x] = v;
  __syncthreads();
  for (int o = 1; o < 256; o <<= 1) {
    int t = (threadIdx.x >= o) ? sh[threadIdx.x - o] : 0;
    __syncthreads();
    sh[threadIdx.x] += t;
    __syncthreads();
  }
  if (i < N) off[i] = sh[threadIdx.x] - v;  // exclusive within block
  if (threadIdx.x == 255) bsum[blockIdx.x] = sh[255];
}

// Exclusive scan of block sums (nb <= 512), one block of 512.
__global__ void __launch_bounds__(512) k_scan2(int* __restrict__ bsum, int nb) {
  __shared__ int sh[512];
  int t = threadIdx.x;
  int v = (t < nb) ? bsum[t] : 0;
  sh[t] = v;
  __syncthreads();
  for (int o = 1; o < 512; o <<= 1) {
    int x = (t >= o) ? sh[t - o] : 0;
    __syncthreads();
    sh[t] += x;
    __syncthreads();
  }
  if (t < nb) bsum[t] = sh[t] - v;
}

// Add block bases; zero cursors; set off[N] = E.
__global__ void __launch_bounds__(256) k_scan3(int* __restrict__ off,
                                               const int* __restrict__ bsum,
                                               int* __restrict__ cur, int N, int E) {
  int i = blockIdx.x * 256 + threadIdx.x;
  if (i < N) { off[i] += bsum[i >> 8]; cur[i] = 0; }
  if (i == N) off[N] = E;
}

// Place src of each edge into its dst's CSR segment.
__global__ void __launch_bounds__(256) k_fill(const int* __restrict__ ei,
                                              const int* __restrict__ off,
                                              int* __restrict__ cur,
                                              int* __restrict__ ssrc, int M, int E) {
  int e = blockIdx.x * blockDim.x + threadIdx.x;
  if (e >= E) return;
  int s, d;
  if (e < M) { s = ei[e]; d = ei[M + e]; } else { s = e - M; d = s; }
  int pos = off[d] + atomicAdd(&cur[d], 1);
  ssrc[pos] = s;
}

// ---------------------------------------------------------------------------
// K_prep: fold attention vectors into input space.
// ---------------------------------------------------------------------------
__global__ void k_prep(const float* __restrict__ W1, const float* __restrict__ as1,
                       const float* __restrict__ ad1,
                       const float* __restrict__ W2, const float* __restrict__ as2,
                       const float* __restrict__ ad2,
                       float* __restrict__ wa1s, float* __restrict__ wa1d,
                       float* __restrict__ wa2s, float* __restrict__ wa2d) {
  int t = threadIdx.x;  // 512 threads
  if (t < 92) {
    int h = t / 23, c = t % 23;
    float s1 = 0.f, s2 = 0.f;
    for (int dd = 0; dd < 32; ++dd) {
      float w = W1[(h * 32 + dd) * 23 + c];
      s1 += w * as1[h * 32 + dd];
      s2 += w * ad1[h * 32 + dd];
    }
    wa1s[t] = s1;
    wa1d[t] = s2;
  }
  {
    int h = t >> 7, c = t & 127;
    float s1 = 0.f, s2 = 0.f;
    for (int dd = 0; dd < 32; ++dd) {
      float w = W2[(h * 32 + dd) * 128 + c];
      s1 += w * as2[h * 32 + dd];
      s2 += w * ad2[h * 32 + dd];
    }
    wa2s[t] = s1;
    wa2d[t] = s2;
  }
}

// ---------------------------------------------------------------------------
// K_g1: g1[n,k] = h_n . W1[k,:], plus folded attention logits.
// ---------------------------------------------------------------------------
__global__ void __launch_bounds__(128) k_g1(
    const float* __restrict__ x, const float* __restrict__ u,
    const float* __restrict__ W1,
    const float* __restrict__ wa1s, const float* __restrict__ wa1d,
    float* __restrict__ g1, float* __restrict__ al1s, float* __restrict__ al1d) {
  int n = blockIdx.x, k = threadIdx.x;
  __shared__ float hs[23];
  if (k < 12) hs[k] = x[n * 12 + k];
  else if (k < 23) hs[k] = u[k - 12];
  __syncthreads();
  const float* w = W1 + k * 23;
  float s = 0.f;
#pragma unroll
  for (int c = 0; c < 23; ++c) s += hs[c] * w[c];
  g1[n * 128 + k] = s;
  if (k < 8) {
    int h = k & 3;
    const float* wa = (k < 4 ? wa1s : wa1d) + h * 23;
    float t = 0.f;
#pragma unroll
    for (int c = 0; c < 23; ++c) t += hs[c] * wa[c];
    (k < 4 ? al1s : al1d)[n * 4 + h] = t;
  }
}

// ---------------------------------------------------------------------------
// K_gat: fused attention + softmax + aggregate per dst node via CSR gather.
// ---------------------------------------------------------------------------
template <int MODE>
__global__ void __launch_bounds__(128) k_gat(
    const float* __restrict__ g, const float* __restrict__ als,
    const float* __restrict__ ald, const int* __restrict__ off,
    const int* __restrict__ ssrc, const float* __restrict__ bias,
    float* __restrict__ outp) {
  int d = blockIdx.x, t = threadIdx.x, h = t >> 5;
  float av = ald[d * 4 + h];
  int p0 = off[d], p1 = off[d + 1];
  float acc = 0.f, den = 0.f;
  int sA = ssrc[p0];  // deg >= 1 (self-loop)
  for (int p = p0; p < p1;) {
    int s = sA;
    int pn = p + 1;
    if (pn < p1) sA = ssrc[pn];
    float w = __expf(leakyf(als[s * 4 + h] + av));
    acc += w * g[(size_t)s * 128 + t];
    den += w;
    p = pn;
  }
  float v = acc / den;
  if (MODE == 0) {
    outp[(size_t)d * 128 + t] = eluf(v + bias[t]);
  } else {
    __shared__ float sh[128];
    sh[t] = v;
    __syncthreads();
    if (t < 32) {
      float m = 0.25f * (sh[t] + sh[t + 32] + sh[t + 64] + sh[t + 96]);
      outp[(size_t)d * 32 + t] = eluf(m + bias[t]);
    }
  }
}

// ---------------------------------------------------------------------------
// K_g2t: LDS-tiled GEMM  g2[n,c] = sum_k h2[n,k] * W2[c,k]  (+ fused al2).
// Block = 128 threads. Whole W2 (64 KB) staged once per block, XOR-swizzled
// in float4 slots so lanes reading 32 different rows at same k hit distinct
// 16B slots (row stride 512B would otherwise be a 32-way bank conflict).
// Thread: m = t&31 -> channels c0=4m..4m+3 ; grp = t>>5 -> 8 nodes.
// Tile = 32 nodes; grid-stride over tiles; h2 tile reread per tile (16 KB).
// ---------------------------------------------------------------------------
__global__ void __launch_bounds__(128) k_g2t(
    const float* __restrict__ h2, const float* __restrict__ W2,
    const float* __restrict__ wa2s, const float* __restrict__ wa2d,
    float* __restrict__ g2, float* __restrict__ al2s, float* __restrict__ al2d,
    int N, int ntiles) {
  __shared__ float4 w4s[128][32];  // 64 KB, [c][slot]
  __shared__ float4 hs4[32][32];   // 16 KB, [node][k4]
  int t = threadIdx.x;

  // stage W2 with swizzle: w4s[c][kk ^ ((c>>2)&31)] = W2[c][4kk..4kk+3]
  for (int i = t; i < 4096; i += 128) {
    int c = i >> 5, kk = i & 31;
    float4 v = *(const float4*)(W2 + c * 128 + kk * 4);
    w4s[c][kk ^ ((c >> 2) & 31)] = v;
  }

  int m = t & 31, grp = t >> 5;
  int c0 = 4 * m;

  for (int tile = blockIdx.x; tile < ntiles; tile += gridDim.x) {
    int n0 = tile * 32;
    __syncthreads();  // prev-tile readers done before overwrite (also covers W2 stage)
    for (int i = t; i < 1024; i += 128) {
      int n = i >> 5, kk = i & 31;
      int nn = n0 + n;
      hs4[n][kk] = (nn < N) ? *(const float4*)(h2 + (size_t)nn * 128 + kk * 4)
                            : make_float4(0.f, 0.f, 0.f, 0.f);
    }
    __syncthreads();

    float acc[8][4];
#pragma unroll
    for (int n = 0; n < 8; ++n)
#pragma unroll
      for (int j = 0; j < 4; ++j) acc[n][j] = 0.f;

#pragma unroll 8
    for (int kk = 0; kk < 32; ++kk) {
      float4 wj[4];
#pragma unroll
      for (int j = 0; j < 4; ++j) wj[j] = w4s[c0 + j][kk ^ m];
#pragma unroll
      for (int n = 0; n < 8; ++n) {
        float4 hv = hs4[grp * 8 + n][kk];
#pragma unroll
        for (int j = 0; j < 4; ++j) {
          acc[n][j] += hv.x * wj[j].x + hv.y * wj[j].y +
                       hv.z * wj[j].z + hv.w * wj[j].w;
        }
      }
    }
#pragma unroll
    for (int n = 0; n < 8; ++n) {
      int nn = n0 + grp * 8 + n;
      if (nn < N)
        *(float4*)(g2 + (size_t)nn * 128 + c0) =
            make_float4(acc[n][0], acc[n][1], acc[n][2], acc[n][3]);
    }

    // fused al2: 32 nodes x 8 (4 src-heads + 4 dst-heads) = 256 dots of 128
    for (int v = 0; v < 2; ++v) {
      int idx = t + 128 * v;
      int n = idx >> 3, j = idx & 7, h = j & 3;
      int nn = n0 + n;
      if (nn < N) {
        const float4* wa = (const float4*)((j < 4 ? wa2s : wa2d) + h * 128);
        float s = 0.f;
#pragma unroll
        for (int kk = 0; kk < 32; ++kk) {
          float4 a = hs4[n][kk];
          float4 w = wa[kk];
          s += a.x * w.x + a.y * w.y + a.z * w.z + a.w * w.w;
        }
        (j < 4 ? al2s : al2d)[(size_t)nn * 4 + h] = s;
      }
    }
  }
}

// ---------------------------------------------------------------------------
// K_dec: per-edge MLP 69->64->32->4. Weights staged in LDS (broadcast reads);
// activations in registers, phase-structured to cap pressure.
// ---------------------------------------------------------------------------
__global__ void __launch_bounds__(256) k_dec(
    const float* __restrict__ h3, const int* __restrict__ ei,
    const float* __restrict__ ea,
    const float* __restrict__ dw1, const float* __restrict__ db1,
    const float* __restrict__ dw2, const float* __restrict__ db2,
    const float* __restrict__ dw3, const float* __restrict__ db3,
    float* __restrict__ out, int M) {
  __shared__ float w1s[64 * 72];  // [k][c], c padded 69->72 (16B-aligned rows)
  __shared__ float w2s[32 * 64];
  __shared__ float w3s[4 * 32];
  __shared__ float bbs[104];
  int t = threadIdx.x;
  for (int i = t; i < 64 * 72; i += 256) {
    int k = i / 72, c = i - k * 72;
    w1s[i] = (c < 69) ? dw1[k * 69 + c] : 0.f;
  }
  for (int i = t; i < 32 * 64; i += 256) w2s[i] = dw2[i];
  if (t < 128) w3s[t] = dw3[t];
  if (t < 64) bbs[t] = db1[t];
  else if (t < 96) bbs[t] = db2[t - 64];
  else if (t < 100) bbs[t] = db3[t - 96];
  __syncthreads();

  int m = blockIdx.x * 256 + t;
  if (m >= M) return;
  int s = ei[m], d = ei[M + m];

  float z1[64];
#pragma unroll
  for (int k = 0; k < 64; ++k) z1[k] = bbs[k];

  // phase A: src features (cols 0..31)
  {
    const float4* hp = (const float4*)(h3 + (size_t)s * 32);
    float4 q[8];
#pragma unroll
    for (int i = 0; i < 8; ++i) q[i] = hp[i];
#pragma unroll
    for (int cq = 0; cq < 8; ++cq) {
      float4 e = q[cq];
#pragma unroll
      for (int k = 0; k < 64; ++k) {
        float4 w = *(const float4*)(w1s + k * 72 + cq * 4);
        z1[k] += e.x * w.x + e.y * w.y + e.z * w.z + e.w * w.w;
      }
    }
  }
  // phase B: dst features (cols 32..63)
  {
    const float4* hp = (const float4*)(h3 + (size_t)d * 32);
    float4 q[8];
#pragma unroll
    for (int i = 0; i < 8; ++i) q[i] = hp[i];
#pragma unroll
    for (int cq = 0; cq < 8; ++cq) {
      float4 e = q[cq];
#pragma unroll
      for (int k = 0; k < 64; ++k) {
        float4 w = *(const float4*)(w1s + k * 72 + 32 + cq * 4);
        z1[k] += e.x * w.x + e.y * w.y + e.z * w.z + e.w * w.w;
      }
    }
  }
  // phase C: edge attrs (cols 64..68)
  {
    const float* ep = ea + (size_t)m * 5;
    float4 e = make_float4(ep[0], ep[1], ep[2], ep[3]);
    float e4 = ep[4];
#pragma unroll
    for (int k = 0; k < 64; ++k) {
      float4 w = *(const float4*)(w1s + k * 72 + 64);
      z1[k] += e.x * w.x + e.y * w.y + e.z * w.z + e.w * w.w +
               e4 * w1s[k * 72 + 68];
    }
  }
#pragma unroll
  for (int k = 0; k < 64; ++k) z1[k] = fmaxf(z1[k], 0.f);

  // layer 2: 64 -> 32
  float z2[32];
#pragma unroll
  for (int k = 0; k < 32; ++k) z2[k] = bbs[64 + k];
#pragma unroll
  for (int cq = 0; cq < 16; ++cq) {
    float4 e = make_float4(z1[cq * 4], z1[cq * 4 + 1], z1[cq * 4 + 2],
                           z1[cq * 4 + 3]);
#pragma unroll
    for (int k = 0; k < 32; ++k) {
      float4 w = *(const float4*)(w2s + k * 64 + cq * 4);
      z2[k] += e.x * w.x + e.y * w.y + e.z * w.z + e.w * w.w;
    }
  }
#pragma unroll
  for (int k = 0; k < 32; ++k) z2[k] = fmaxf(z2[k], 0.f);

  // layer 3: 32 -> 4
  float o0 = bbs[96], o1 = bbs[97], o2 = bbs[98], o3 = bbs[99];
#pragma unroll
  for (int cq = 0; cq < 8; ++cq) {
    float4 e = make_float4(z2[cq * 4], z2[cq * 4 + 1], z2[cq * 4 + 2],
                           z2[cq * 4 + 3]);
    float4 wa = *(const float4*)(w3s + 0 * 32 + cq * 4);
    float4 wb = *(const float4*)(w3s + 1 * 32 + cq * 4);
    float4 wc = *(const float4*)(w3s + 2 * 32 + cq * 4);
    float4 wd = *(const float4*)(w3s + 3 * 32 + cq * 4);
    o0 += e.x * wa.x + e.y * wa.y + e.z * wa.z + e.w * wa.w;
    o1 += e.x * wb.x + e.y * wb.y + e.z * wb.z + e.w * wb.w;
    o2 += e.x * wc.x + e.y * wc.y + e.z * wc.z + e.w * wc.w;
    o3 += e.x * wd.x + e.y * wd.y + e.z * wd.z + e.w * wd.w;
  }
  *(float4*)(out + (size_t)m * 4) = make_float4(o0, o1, o2, o3);
}

// ---------------------------------------------------------------------------
extern "C" void kernel_launch(void* const* d_in, const int* in_sizes, int n_in,
                              void* d_out, int out_size, void* d_ws, size_t ws_size,
                              hipStream_t stream) {
  const float* x   = (const float*)d_in[0];
  const int*   ei  = (const int*)d_in[1];
  const float* ea  = (const float*)d_in[2];
  const float* u   = (const float*)d_in[3];
  const float* W1  = (const float*)d_in[4];
  const float* as1 = (const float*)d_in[5];
  const float* ad1 = (const float*)d_in[6];
  const float* b1  = (const float*)d_in[7];
  const float* W2  = (const float*)d_in[8];
  const float* as2 = (const float*)d_in[9];
  const float* ad2 = (const float*)d_in[10];
  const float* b2  = (const float*)d_in[11];
  const float* dw1 = (const float*)d_in[12];
  const float* db1 = (const float*)d_in[13];
  const float* dw2 = (const float*)d_in[14];
  const float* db2 = (const float*)d_in[15];
  const float* dw3 = (const float*)d_in[16];
  const float* db3 = (const float*)d_in[17];
  float* out = (float*)d_out;

  const int N = in_sizes[0] / 12;
  const int M = in_sizes[1] / 2;
  const int E = M + N;

  float* ws = (float*)d_ws;
  float* A    = ws;                      // N*128: g1, then g2
  float* B    = A + (size_t)N * 128;     // N*128: h2 (conv1 output, fused epilogue)
  float* H3   = B + (size_t)N * 128;     // N*32
  float* AL1S = H3 + (size_t)N * 32;     // N*4 each below
  float* AL1D = AL1S + (size_t)N * 4;
  float* AL2S = AL1D + (size_t)N * 4;
  float* AL2D = AL2S + (size_t)N * 4;
  float* WA1S = AL2D + (size_t)N * 4;    // 96 (4x23 padded)
  float* WA1D = WA1S + 96;
  float* WA2S = WA1D + 96;               // 512 (4x128)
  float* WA2D = WA2S + 512;
  // int region
  int* IOFF = (int*)(WA2D + 512);        // N+1
  int* ICUR = IOFF + (N + 1);            // N (counts, then cursors)
  int* IBS  = ICUR + N;                  // 512 block sums
  int* ISRC = IBS + 512;                 // E sorted srcs

  int nb = (N + 255) / 256;
  int gE = (E + 255) / 256;

  // --- CSR build (once, reused by both convs) ---
  k_izero<<<nb, 256, 0, stream>>>(ICUR, N);
  k_count<<<gE, 256, 0, stream>>>(ei, ICUR, M, E);
  k_scan1<<<nb, 256, 0, stream>>>(ICUR, IOFF, IBS, N);
  k_scan2<<<1, 512, 0, stream>>>(IBS, nb);
  k_scan3<<<(N + 256) / 256, 256, 0, stream>>>(IOFF, IBS, ICUR, N, E);
  k_fill<<<gE, 256, 0, stream>>>(ei, IOFF, ICUR, ISRC, M, E);

  k_prep<<<1, 512, 0, stream>>>(W1, as1, ad1, W2, as2, ad2, WA1S, WA1D, WA2S, WA2D);

  // --- conv1 ---
  k_g1<<<N, 128, 0, stream>>>(x, u, W1, WA1S, WA1D, A, AL1S, AL1D);
  k_gat<0><<<N, 128, 0, stream>>>(A, AL1S, AL1D, IOFF, ISRC, b1, B);

  // --- conv2 ---
  int ntiles = (N + 31) / 32;
  k_g2t<<<512, 128, 0, stream>>>(B, W2, WA2S, WA2D, A, AL2S, AL2D, N, ntiles);
  k_gat<1><<<N, 128, 0, stream>>>(A, AL2S, AL2D, IOFF, ISRC, b2, H3);

  // --- decoder ---
  k_dec<<<(M + 255) / 256, 256, 0, stream>>>(H3, ei, ea, dw1, db1, dw2, db2,
                                             dw3, db3, out, M);
}

// Round 5
// 1240.112 us; speedup vs baseline: 6.7087x; 1.2075x over previous
//
#include <hip/hip_runtime.h>

#define DEVINL __device__ __forceinline__

DEVINL float leakyf(float v) { return v > 0.f ? v : 0.2f * v; }
DEVINL float eluf(float v)   { return v > 0.f ? v : __expf(v) - 1.f; }

// ---------------------------------------------------------------------------
// int zero fill
// ---------------------------------------------------------------------------
__global__ void __launch_bounds__(256) k_izero(int* __restrict__ p, int total) {
  int t = blockIdx.x * blockDim.x + threadIdx.x;
  if (t < total) p[t] = 0;
}

// ---------------------------------------------------------------------------
// CSR build: count incoming edges per dst (self-loops appended, e >= M).
// ---------------------------------------------------------------------------
__global__ void __launch_bounds__(256) k_count(const int* __restrict__ ei,
                                               int* __restrict__ cnt, int M, int E) {
  int e = blockIdx.x * blockDim.x + threadIdx.x;
  if (e >= E) return;
  int d = (e < M) ? ei[M + e] : e - M;
  atomicAdd(&cnt[d], 1);
}

// Per-256-block exclusive scan; block totals to bsum.
__global__ void __launch_bounds__(256) k_scan1(const int* __restrict__ cnt,
                                               int* __restrict__ off,
                                               int* __restrict__ bsum, int N) {
  __shared__ int sh[256];
  int i = blockIdx.x * 256 + threadIdx.x;
  int v = (i < N) ? cnt[i] : 0;
  sh[threadIdx.x] = v;
  __syncthreads();
  for (int o = 1; o < 256; o <<= 1) {
    int t = (threadIdx.x >= o) ? sh[threadIdx.x - o] : 0;
    __syncthreads();
    sh[threadIdx.x] += t;
    __syncthreads();
  }
  if (i < N) off[i] = sh[threadIdx.x] - v;  // exclusive within block
  if (threadIdx.x == 255) bsum[blockIdx.x] = sh[255];
}

// Exclusive scan of block sums (nb <= 512), one block of 512.
__global__ void __launch_bounds__(512) k_scan2(int* __restrict__ bsum, int nb) {
  __shared__ int sh[512];
  int t = threadIdx.x;
  int v = (t < nb) ? bsum[t] : 0;
  sh[t] = v;
  __syncthreads();
  for (int o = 1; o < 512; o <<= 1) {
    int x = (t >= o) ? sh[t - o] : 0;
    __syncthreads();
    sh[t] += x;
    __syncthreads();
  }
  if (t < nb) bsum[t] = sh[t] - v;
}

// Add block bases; zero cursors; set off[N] = E.
__global__ void __launch_bounds__(256) k_scan3(int* __restrict__ off,
                                               const int* __restrict__ bsum,
                                               int* __restrict__ cur, int N, int E) {
  int i = blockIdx.x * 256 + threadIdx.x;
  if (i < N) { off[i] += bsum[i >> 8]; cur[i] = 0; }
  if (i == N) off[N] = E;
}

// Place src of each edge into its dst's CSR segment.
__global__ void __launch_bounds__(256) k_fill(const int* __restrict__ ei,
                                              const int* __restrict__ off,
                                              int* __restrict__ cur,
                                              int* __restrict__ ssrc, int M, int E) {
  int e = blockIdx.x * blockDim.x + threadIdx.x;
  if (e >= E) return;
  int s, d;
  if (e < M) { s = ei[e]; d = ei[M + e]; } else { s = e - M; d = s; }
  int pos = off[d] + atomicAdd(&cur[d], 1);
  ssrc[pos] = s;
}

// ---------------------------------------------------------------------------
// K_prep: fold attention vectors into input space.
// ---------------------------------------------------------------------------
__global__ void k_prep(const float* __restrict__ W1, const float* __restrict__ as1,
                       const float* __restrict__ ad1,
                       const float* __restrict__ W2, const float* __restrict__ as2,
                       const float* __restrict__ ad2,
                       float* __restrict__ wa1s, float* __restrict__ wa1d,
                       float* __restrict__ wa2s, float* __restrict__ wa2d) {
  int t = threadIdx.x;  // 512 threads
  if (t < 92) {
    int h = t / 23, c = t % 23;
    float s1 = 0.f, s2 = 0.f;
    for (int dd = 0; dd < 32; ++dd) {
      float w = W1[(h * 32 + dd) * 23 + c];
      s1 += w * as1[h * 32 + dd];
      s2 += w * ad1[h * 32 + dd];
    }
    wa1s[t] = s1;
    wa1d[t] = s2;
  }
  {
    int h = t >> 7, c = t & 127;
    float s1 = 0.f, s2 = 0.f;
    for (int dd = 0; dd < 32; ++dd) {
      float w = W2[(h * 32 + dd) * 128 + c];
      s1 += w * as2[h * 32 + dd];
      s2 += w * ad2[h * 32 + dd];
    }
    wa2s[t] = s1;
    wa2d[t] = s2;
  }
}

// ---------------------------------------------------------------------------
// K_g1: g1[n,k] = h_n . W1[k,:], plus folded attention logits.
// ---------------------------------------------------------------------------
__global__ void __launch_bounds__(128) k_g1(
    const float* __restrict__ x, const float* __restrict__ u,
    const float* __restrict__ W1,
    const float* __restrict__ wa1s, const float* __restrict__ wa1d,
    float* __restrict__ g1, float* __restrict__ al1s, float* __restrict__ al1d) {
  int n = blockIdx.x, k = threadIdx.x;
  __shared__ float hs[23];
  if (k < 12) hs[k] = x[n * 12 + k];
  else if (k < 23) hs[k] = u[k - 12];
  __syncthreads();
  const float* w = W1 + k * 23;
  float s = 0.f;
#pragma unroll
  for (int c = 0; c < 23; ++c) s += hs[c] * w[c];
  g1[n * 128 + k] = s;
  if (k < 8) {
    int h = k & 3;
    const float* wa = (k < 4 ? wa1s : wa1d) + h * 23;
    float t = 0.f;
#pragma unroll
    for (int c = 0; c < 23; ++c) t += hs[c] * wa[c];
    (k < 4 ? al1s : al1d)[n * 4 + h] = t;
  }
}

// ---------------------------------------------------------------------------
// K_gat: fused attention + softmax + aggregate per dst node via CSR gather.
// ---------------------------------------------------------------------------
template <int MODE>
__global__ void __launch_bounds__(128) k_gat(
    const float* __restrict__ g, const float* __restrict__ als,
    const float* __restrict__ ald, const int* __restrict__ off,
    const int* __restrict__ ssrc, const float* __restrict__ bias,
    float* __restrict__ outp) {
  int d = blockIdx.x, t = threadIdx.x, h = t >> 5;
  float av = ald[d * 4 + h];
  int p0 = off[d], p1 = off[d + 1];
  float acc = 0.f, den = 0.f;
  int sA = ssrc[p0];  // deg >= 1 (self-loop)
  for (int p = p0; p < p1;) {
    int s = sA;
    int pn = p + 1;
    if (pn < p1) sA = ssrc[pn];
    float w = __expf(leakyf(als[s * 4 + h] + av));
    acc += w * g[(size_t)s * 128 + t];
    den += w;
    p = pn;
  }
  float v = acc / den;
  if (MODE == 0) {
    outp[(size_t)d * 128 + t] = eluf(v + bias[t]);
  } else {
    __shared__ float sh[128];
    sh[t] = v;
    __syncthreads();
    if (t < 32) {
      float m = 0.25f * (sh[t] + sh[t + 32] + sh[t + 64] + sh[t + 96]);
      outp[(size_t)d * 32 + t] = eluf(m + bias[t]);
    }
  }
}

// ---------------------------------------------------------------------------
// K_g2t: LDS-tiled GEMM  g2[n,c] = sum_k h2[n,k] * W2[c,k]  (+ fused al2).
// ---------------------------------------------------------------------------
__global__ void __launch_bounds__(128) k_g2t(
    const float* __restrict__ h2, const float* __restrict__ W2,
    const float* __restrict__ wa2s, const float* __restrict__ wa2d,
    float* __restrict__ g2, float* __restrict__ al2s, float* __restrict__ al2d,
    int N, int ntiles) {
  __shared__ float4 w4s[128][32];  // 64 KB, [c][slot]
  __shared__ float4 hs4[32][32];   // 16 KB, [node][k4]
  int t = threadIdx.x;

  // stage W2 with swizzle: w4s[c][kk ^ ((c>>2)&31)] = W2[c][4kk..4kk+3]
  for (int i = t; i < 4096; i += 128) {
    int c = i >> 5, kk = i & 31;
    float4 v = *(const float4*)(W2 + c * 128 + kk * 4);
    w4s[c][kk ^ ((c >> 2) & 31)] = v;
  }

  int m = t & 31, grp = t >> 5;
  int c0 = 4 * m;

  for (int tile = blockIdx.x; tile < ntiles; tile += gridDim.x) {
    int n0 = tile * 32;
    __syncthreads();  // prev-tile readers done before overwrite (also covers W2 stage)
    for (int i = t; i < 1024; i += 128) {
      int n = i >> 5, kk = i & 31;
      int nn = n0 + n;
      hs4[n][kk] = (nn < N) ? *(const float4*)(h2 + (size_t)nn * 128 + kk * 4)
                            : make_float4(0.f, 0.f, 0.f, 0.f);
    }
    __syncthreads();

    float acc[8][4];
#pragma unroll
    for (int n = 0; n < 8; ++n)
#pragma unroll
      for (int j = 0; j < 4; ++j) acc[n][j] = 0.f;

#pragma unroll 8
    for (int kk = 0; kk < 32; ++kk) {
      float4 wj[4];
#pragma unroll
      for (int j = 0; j < 4; ++j) wj[j] = w4s[c0 + j][kk ^ m];
#pragma unroll
      for (int n = 0; n < 8; ++n) {
        float4 hv = hs4[grp * 8 + n][kk];
#pragma unroll
        for (int j = 0; j < 4; ++j) {
          acc[n][j] += hv.x * wj[j].x + hv.y * wj[j].y +
                       hv.z * wj[j].z + hv.w * wj[j].w;
        }
      }
    }
#pragma unroll
    for (int n = 0; n < 8; ++n) {
      int nn = n0 + grp * 8 + n;
      if (nn < N)
        *(float4*)(g2 + (size_t)nn * 128 + c0) =
            make_float4(acc[n][0], acc[n][1], acc[n][2], acc[n][3]);
    }

    // fused al2: 32 nodes x 8 (4 src-heads + 4 dst-heads) = 256 dots of 128
    for (int v = 0; v < 2; ++v) {
      int idx = t + 128 * v;
      int n = idx >> 3, j = idx & 7, h = j & 3;
      int nn = n0 + n;
      if (nn < N) {
        const float4* wa = (const float4*)((j < 4 ? wa2s : wa2d) + h * 128);
        float s = 0.f;
#pragma unroll
        for (int kk = 0; kk < 32; ++kk) {
          float4 a = hs4[n][kk];
          float4 w = wa[kk];
          s += a.x * w.x + a.y * w.y + a.z * w.z + a.w * w.w;
        }
        (j < 4 ? al2s : al2d)[(size_t)nn * 4 + h] = s;
      }
    }
  }
}

// ---------------------------------------------------------------------------
// K_pq: per-node fold of decoder layer-1 src/dst blocks.
// pq[n][k]    = sum_c dw1[k][c]      * h3[n][c]   (k<64,  c<32)  "P"
// pq[n][64+k] = sum_c dw1[k][32+c]   * h3[n][c]                  "Q"
// Block = 256 threads, 64-node tile. Weights (64x64) XOR-swizzled in LDS.
// ---------------------------------------------------------------------------
__global__ void __launch_bounds__(256) k_pq(
    const float* __restrict__ h3, const float* __restrict__ dw1,
    float* __restrict__ pq, int N) {
  __shared__ float4 ws4[64][16];  // dw1 cols 0..63 (P|Q), swizzled slots
  __shared__ float ht[64][32];    // h3 tile
  int t = threadIdx.x;
  for (int i = t; i < 4096; i += 256) {
    int k = i >> 6, c = i & 63;
    ((float*)&ws4[k][(c >> 2) ^ (k & 15)])[c & 3] = dw1[k * 69 + c];
  }
  int n0 = blockIdx.x * 64;
  for (int i = t; i < 2048; i += 256) {
    int n = i >> 5, c = i & 31;
    int nn = n0 + n;
    ht[n][c] = (nn < N) ? h3[(size_t)nn * 32 + c] : 0.f;
  }
  __syncthreads();
  int k2 = t & 127, sub = t >> 7;
  int k = k2 & 63, base4 = (k2 < 64) ? 0 : 8;
  float4 wr[8];
#pragma unroll
  for (int i = 0; i < 8; ++i) wr[i] = ws4[k][(base4 + i) ^ (k & 15)];
  for (int ii = 0; ii < 32; ++ii) {
    int n = sub * 32 + ii;
    const float4* hr = (const float4*)ht[n];
    float s = 0.f;
#pragma unroll
    for (int i = 0; i < 8; ++i) {
      float4 a = hr[i], w = wr[i];
      s += a.x * w.x + a.y * w.y + a.z * w.z + a.w * w.w;
    }
    int nn = n0 + n;
    if (nn < N) pq[(size_t)nn * 128 + k2] = s;
  }
}

// ---------------------------------------------------------------------------
// K_dec: per-edge MLP with layer-1 folded:
//   z1 = relu(P[s] + Q[d] + C*ea + b1);  z2 = relu(dw2 z1);  out = dw3 z2.
// LDS only ~11 KB (C, dw2, dw3, biases). Per-edge MACs 2496 (was 6592).
// ---------------------------------------------------------------------------
__global__ void __launch_bounds__(256) k_dec(
    const float* __restrict__ pq, const int* __restrict__ ei,
    const float* __restrict__ ea,
    const float* __restrict__ dw1, const float* __restrict__ db1,
    const float* __restrict__ dw2, const float* __restrict__ db2,
    const float* __restrict__ dw3, const float* __restrict__ db3,
    float* __restrict__ out, int M) {
  __shared__ float cs[64][8];   // dw1 cols 64..68, padded
  __shared__ float w2s[32 * 64];
  __shared__ float w3s[4 * 32];
  __shared__ float bbs[104];
  int t = threadIdx.x;
  for (int i = t; i < 512; i += 256) {
    int k = i >> 3, c = i & 7;
    cs[k][c] = (c < 5) ? dw1[k * 69 + 64 + c] : 0.f;
  }
  for (int i = t; i < 2048; i += 256) w2s[i] = dw2[i];
  if (t < 128) w3s[t] = dw3[t];
  if (t < 64) bbs[t] = db1[t];
  else if (t < 96) bbs[t] = db2[t - 64];
  else if (t < 100) bbs[t] = db3[t - 96];
  __syncthreads();

  int m = blockIdx.x * 256 + t;
  if (m >= M) return;
  int s = ei[m], d = ei[M + m];
  const float4* Pp = (const float4*)(pq + (size_t)s * 128);
  const float4* Qp = (const float4*)(pq + (size_t)d * 128 + 64);
  const float* ep = ea + (size_t)m * 5;
  float e0 = ep[0], e1 = ep[1], e2 = ep[2], e3 = ep[3], e4 = ep[4];

  float z1[64];
#pragma unroll
  for (int i = 0; i < 16; ++i) {
    float4 p = Pp[i], q = Qp[i];
    z1[4 * i + 0] = p.x + q.x;
    z1[4 * i + 1] = p.y + q.y;
    z1[4 * i + 2] = p.z + q.z;
    z1[4 * i + 3] = p.w + q.w;
  }
#pragma unroll
  for (int k = 0; k < 64; ++k) {
    float acc = z1[k] + bbs[k];
    acc += cs[k][0] * e0 + cs[k][1] * e1 + cs[k][2] * e2 + cs[k][3] * e3 +
           cs[k][4] * e4;
    z1[k] = fmaxf(acc, 0.f);
  }

  // layer 2: 64 -> 32
  float z2[32];
#pragma unroll
  for (int k = 0; k < 32; ++k) z2[k] = bbs[64 + k];
#pragma unroll
  for (int cq = 0; cq < 16; ++cq) {
    float4 e = make_float4(z1[cq * 4], z1[cq * 4 + 1], z1[cq * 4 + 2],
                           z1[cq * 4 + 3]);
#pragma unroll
    for (int k = 0; k < 32; ++k) {
      float4 w = *(const float4*)(w2s + k * 64 + cq * 4);
      z2[k] += e.x * w.x + e.y * w.y + e.z * w.z + e.w * w.w;
    }
  }
#pragma unroll
  for (int k = 0; k < 32; ++k) z2[k] = fmaxf(z2[k], 0.f);

  // layer 3: 32 -> 4
  float o0 = bbs[96], o1 = bbs[97], o2 = bbs[98], o3 = bbs[99];
#pragma unroll
  for (int cq = 0; cq < 8; ++cq) {
    float4 e = make_float4(z2[cq * 4], z2[cq * 4 + 1], z2[cq * 4 + 2],
                           z2[cq * 4 + 3]);
    float4 wa = *(const float4*)(w3s + 0 * 32 + cq * 4);
    float4 wb = *(const float4*)(w3s + 1 * 32 + cq * 4);
    float4 wc = *(const float4*)(w3s + 2 * 32 + cq * 4);
    float4 wd = *(const float4*)(w3s + 3 * 32 + cq * 4);
    o0 += e.x * wa.x + e.y * wa.y + e.z * wa.z + e.w * wa.w;
    o1 += e.x * wb.x + e.y * wb.y + e.z * wb.z + e.w * wb.w;
    o2 += e.x * wc.x + e.y * wc.y + e.z * wc.z + e.w * wc.w;
    o3 += e.x * wd.x + e.y * wd.y + e.z * wd.z + e.w * wd.w;
  }
  *(float4*)(out + (size_t)m * 4) = make_float4(o0, o1, o2, o3);
}

// ---------------------------------------------------------------------------
extern "C" void kernel_launch(void* const* d_in, const int* in_sizes, int n_in,
                              void* d_out, int out_size, void* d_ws, size_t ws_size,
                              hipStream_t stream) {
  const float* x   = (const float*)d_in[0];
  const int*   ei  = (const int*)d_in[1];
  const float* ea  = (const float*)d_in[2];
  const float* u   = (const float*)d_in[3];
  const float* W1  = (const float*)d_in[4];
  const float* as1 = (const float*)d_in[5];
  const float* ad1 = (const float*)d_in[6];
  const float* b1  = (const float*)d_in[7];
  const float* W2  = (const float*)d_in[8];
  const float* as2 = (const float*)d_in[9];
  const float* ad2 = (const float*)d_in[10];
  const float* b2  = (const float*)d_in[11];
  const float* dw1 = (const float*)d_in[12];
  const float* db1 = (const float*)d_in[13];
  const float* dw2 = (const float*)d_in[14];
  const float* db2 = (const float*)d_in[15];
  const float* dw3 = (const float*)d_in[16];
  const float* db3 = (const float*)d_in[17];
  float* out = (float*)d_out;

  const int N = in_sizes[0] / 12;
  const int M = in_sizes[1] / 2;
  const int E = M + N;

  float* ws = (float*)d_ws;
  float* A    = ws;                      // N*128: g1 -> g2 -> PQ
  float* B    = A + (size_t)N * 128;     // N*128: h2 (conv1 output, fused epilogue)
  float* H3   = B + (size_t)N * 128;     // N*32
  float* AL1S = H3 + (size_t)N * 32;     // N*4 each below
  float* AL1D = AL1S + (size_t)N * 4;
  float* AL2S = AL1D + (size_t)N * 4;
  float* AL2D = AL2S + (size_t)N * 4;
  float* WA1S = AL2D + (size_t)N * 4;    // 96 (4x23 padded)
  float* WA1D = WA1S + 96;
  float* WA2S = WA1D + 96;               // 512 (4x128)
  float* WA2D = WA2S + 512;
  // int region
  int* IOFF = (int*)(WA2D + 512);        // N+1
  int* ICUR = IOFF + (N + 1);            // N (counts, then cursors)
  int* IBS  = ICUR + N;                  // 512 block sums
  int* ISRC = IBS + 512;                 // E sorted srcs

  int nb = (N + 255) / 256;
  int gE = (E + 255) / 256;

  // --- CSR build (once, reused by both convs) ---
  k_izero<<<nb, 256, 0, stream>>>(ICUR, N);
  k_count<<<gE, 256, 0, stream>>>(ei, ICUR, M, E);
  k_scan1<<<nb, 256, 0, stream>>>(ICUR, IOFF, IBS, N);
  k_scan2<<<1, 512, 0, stream>>>(IBS, nb);
  k_scan3<<<(N + 256) / 256, 256, 0, stream>>>(IOFF, IBS, ICUR, N, E);
  k_fill<<<gE, 256, 0, stream>>>(ei, IOFF, ICUR, ISRC, M, E);

  k_prep<<<1, 512, 0, stream>>>(W1, as1, ad1, W2, as2, ad2, WA1S, WA1D, WA2S, WA2D);

  // --- conv1 ---
  k_g1<<<N, 128, 0, stream>>>(x, u, W1, WA1S, WA1D, A, AL1S, AL1D);
  k_gat<0><<<N, 128, 0, stream>>>(A, AL1S, AL1D, IOFF, ISRC, b1, B);

  // --- conv2 ---
  int ntiles = (N + 31) / 32;
  k_g2t<<<512, 128, 0, stream>>>(B, W2, WA2S, WA2D, A, AL2S, AL2D, N, ntiles);
  k_gat<1><<<N, 128, 0, stream>>>(A, AL2S, AL2D, IOFF, ISRC, b2, H3);

  // --- decoder (A region now dead -> reuse for PQ) ---
  k_pq<<<(N + 63) / 64, 256, 0, stream>>>(H3, dw1, A, N);
  k_dec<<<(M + 255) / 256, 256, 0, stream>>>(A, ei, ea, dw1, db1, dw2, db2,
                                             dw3, db3, out, M);
}

// Round 6
// 1121.668 us; speedup vs baseline: 7.4171x; 1.1056x over previous
//
#include <hip/hip_runtime.h>

#define DEVINL __device__ __forceinline__

DEVINL float leakyf(float v) { return v > 0.f ? v : 0.2f * v; }
DEVINL float eluf(float v)   { return v > 0.f ? v : __expf(v) - 1.f; }

// ---------------------------------------------------------------------------
// int zero fill
// ---------------------------------------------------------------------------
__global__ void __launch_bounds__(256) k_izero(int* __restrict__ p, int total) {
  int t = blockIdx.x * blockDim.x + threadIdx.x;
  if (t < total) p[t] = 0;
}

// ---------------------------------------------------------------------------
// CSR build: count incoming edges per dst (self-loops appended, e >= M).
// ---------------------------------------------------------------------------
__global__ void __launch_bounds__(256) k_count(const int* __restrict__ ei,
                                               int* __restrict__ cnt, int M, int E) {
  int e = blockIdx.x * blockDim.x + threadIdx.x;
  if (e >= E) return;
  int d = (e < M) ? ei[M + e] : e - M;
  atomicAdd(&cnt[d], 1);
}

// Per-256-block exclusive scan; block totals to bsum.
__global__ void __launch_bounds__(256) k_scan1(const int* __restrict__ cnt,
                                               int* __restrict__ off,
                                               int* __restrict__ bsum, int N) {
  __shared__ int sh[256];
  int i = blockIdx.x * 256 + threadIdx.x;
  int v = (i < N) ? cnt[i] : 0;
  sh[threadIdx.x] = v;
  __syncthreads();
  for (int o = 1; o < 256; o <<= 1) {
    int t = (threadIdx.x >= o) ? sh[threadIdx.x - o] : 0;
    __syncthreads();
    sh[threadIdx.x] += t;
    __syncthreads();
  }
  if (i < N) off[i] = sh[threadIdx.x] - v;  // exclusive within block
  if (threadIdx.x == 255) bsum[blockIdx.x] = sh[255];
}

// Exclusive scan of block sums (nb <= 512), one block of 512.
__global__ void __launch_bounds__(512) k_scan2(int* __restrict__ bsum, int nb) {
  __shared__ int sh[512];
  int t = threadIdx.x;
  int v = (t < nb) ? bsum[t] : 0;
  sh[t] = v;
  __syncthreads();
  for (int o = 1; o < 512; o <<= 1) {
    int x = (t >= o) ? sh[t - o] : 0;
    __syncthreads();
    sh[t] += x;
    __syncthreads();
  }
  if (t < nb) bsum[t] = sh[t] - v;
}

// Add block bases; zero cursors; set off[N] = E.
__global__ void __launch_bounds__(256) k_scan3(int* __restrict__ off,
                                               const int* __restrict__ bsum,
                                               int* __restrict__ cur, int N, int E) {
  int i = blockIdx.x * 256 + threadIdx.x;
  if (i < N) { off[i] += bsum[i >> 8]; cur[i] = 0; }
  if (i == N) off[N] = E;
}

// Place (src, dst, orig-edge-id) of each edge into its dst's CSR segment.
__global__ void __launch_bounds__(256) k_fill(const int* __restrict__ ei,
                                              const int* __restrict__ off,
                                              int* __restrict__ cur,
                                              int* __restrict__ ssrc,
                                              int* __restrict__ idst,
                                              int* __restrict__ ieid, int M, int E) {
  int e = blockIdx.x * blockDim.x + threadIdx.x;
  if (e >= E) return;
  int s, d, id;
  if (e < M) { s = ei[e]; d = ei[M + e]; id = e; }
  else       { s = e - M; d = s; id = -1; }
  int pos = off[d] + atomicAdd(&cur[d], 1);
  ssrc[pos] = s;
  idst[pos] = d;
  ieid[pos] = id;
}

// ---------------------------------------------------------------------------
// K_prep: fold attention vectors into input space.
// ---------------------------------------------------------------------------
__global__ void k_prep(const float* __restrict__ W1, const float* __restrict__ as1,
                       const float* __restrict__ ad1,
                       const float* __restrict__ W2, const float* __restrict__ as2,
                       const float* __restrict__ ad2,
                       float* __restrict__ wa1s, float* __restrict__ wa1d,
                       float* __restrict__ wa2s, float* __restrict__ wa2d) {
  int t = threadIdx.x;  // 512 threads
  if (t < 92) {
    int h = t / 23, c = t % 23;
    float s1 = 0.f, s2 = 0.f;
    for (int dd = 0; dd < 32; ++dd) {
      float w = W1[(h * 32 + dd) * 23 + c];
      s1 += w * as1[h * 32 + dd];
      s2 += w * ad1[h * 32 + dd];
    }
    wa1s[t] = s1;
    wa1d[t] = s2;
  }
  {
    int h = t >> 7, c = t & 127;
    float s1 = 0.f, s2 = 0.f;
    for (int dd = 0; dd < 32; ++dd) {
      float w = W2[(h * 32 + dd) * 128 + c];
      s1 += w * as2[h * 32 + dd];
      s2 += w * ad2[h * 32 + dd];
    }
    wa2s[t] = s1;
    wa2d[t] = s2;
  }
}

// ---------------------------------------------------------------------------
// K_g1: g1[n,k] = h_n . W1[k,:], plus folded attention logits.
// ---------------------------------------------------------------------------
__global__ void __launch_bounds__(128) k_g1(
    const float* __restrict__ x, const float* __restrict__ u,
    const float* __restrict__ W1,
    const float* __restrict__ wa1s, const float* __restrict__ wa1d,
    float* __restrict__ g1, float* __restrict__ al1s, float* __restrict__ al1d) {
  int n = blockIdx.x, k = threadIdx.x;
  __shared__ float hs[23];
  if (k < 12) hs[k] = x[n * 12 + k];
  else if (k < 23) hs[k] = u[k - 12];
  __syncthreads();
  const float* w = W1 + k * 23;
  float s = 0.f;
#pragma unroll
  for (int c = 0; c < 23; ++c) s += hs[c] * w[c];
  g1[n * 128 + k] = s;
  if (k < 8) {
    int h = k & 3;
    const float* wa = (k < 4 ? wa1s : wa1d) + h * 23;
    float t = 0.f;
#pragma unroll
    for (int c = 0; c < 23; ++c) t += hs[c] * wa[c];
    (k < 4 ? al1s : al1d)[n * 4 + h] = t;
  }
}

// ---------------------------------------------------------------------------
// K_gat: fused attention + softmax + aggregate per dst node via CSR gather.
// 4-wide unrolled: 4 independent {ssrc -> als -> g-row} chains in flight.
// ---------------------------------------------------------------------------
template <int MODE>
__global__ void __launch_bounds__(128) k_gat(
    const float* __restrict__ g, const float* __restrict__ als,
    const float* __restrict__ ald, const int* __restrict__ off,
    const int* __restrict__ ssrc, const float* __restrict__ bias,
    float* __restrict__ outp) {
  int d = blockIdx.x, t = threadIdx.x, h = t >> 5;
  float av = ald[d * 4 + h];
  int p0 = off[d], p1 = off[d + 1];
  float acc = 0.f, den = 0.f;
  int p = p0;
  for (; p + 4 <= p1; p += 4) {
    int s0 = ssrc[p], s1 = ssrc[p + 1], s2 = ssrc[p + 2], s3 = ssrc[p + 3];
    float l0 = als[s0 * 4 + h], l1 = als[s1 * 4 + h];
    float l2 = als[s2 * 4 + h], l3 = als[s3 * 4 + h];
    float g0 = g[(size_t)s0 * 128 + t], g1v = g[(size_t)s1 * 128 + t];
    float g2v = g[(size_t)s2 * 128 + t], g3v = g[(size_t)s3 * 128 + t];
    float w0 = __expf(leakyf(l0 + av)), w1 = __expf(leakyf(l1 + av));
    float w2 = __expf(leakyf(l2 + av)), w3 = __expf(leakyf(l3 + av));
    acc += w0 * g0 + w1 * g1v + w2 * g2v + w3 * g3v;
    den += (w0 + w1) + (w2 + w3);
  }
  for (; p < p1; ++p) {
    int s = ssrc[p];
    float w = __expf(leakyf(als[s * 4 + h] + av));
    acc += w * g[(size_t)s * 128 + t];
    den += w;
  }
  float v = acc / den;
  if (MODE == 0) {
    outp[(size_t)d * 128 + t] = eluf(v + bias[t]);
  } else {
    __shared__ float sh[128];
    sh[t] = v;
    __syncthreads();
    if (t < 32) {
      float m = 0.25f * (sh[t] + sh[t + 32] + sh[t + 64] + sh[t + 96]);
      outp[(size_t)d * 32 + t] = eluf(m + bias[t]);
    }
  }
}

// ---------------------------------------------------------------------------
// K_g2t: LDS-tiled GEMM  g2[n,c] = sum_k h2[n,k] * W2[c,k]  (+ fused al2).
// ---------------------------------------------------------------------------
__global__ void __launch_bounds__(128) k_g2t(
    const float* __restrict__ h2, const float* __restrict__ W2,
    const float* __restrict__ wa2s, const float* __restrict__ wa2d,
    float* __restrict__ g2, float* __restrict__ al2s, float* __restrict__ al2d,
    int N, int ntiles) {
  __shared__ float4 w4s[128][32];  // 64 KB, [c][slot]
  __shared__ float4 hs4[32][32];   // 16 KB, [node][k4]
  int t = threadIdx.x;

  // stage W2 with swizzle: w4s[c][kk ^ ((c>>2)&31)] = W2[c][4kk..4kk+3]
  for (int i = t; i < 4096; i += 128) {
    int c = i >> 5, kk = i & 31;
    float4 v = *(const float4*)(W2 + c * 128 + kk * 4);
    w4s[c][kk ^ ((c >> 2) & 31)] = v;
  }

  int m = t & 31, grp = t >> 5;
  int c0 = 4 * m;

  for (int tile = blockIdx.x; tile < ntiles; tile += gridDim.x) {
    int n0 = tile * 32;
    __syncthreads();  // prev-tile readers done before overwrite (also covers W2 stage)
    for (int i = t; i < 1024; i += 128) {
      int n = i >> 5, kk = i & 31;
      int nn = n0 + n;
      hs4[n][kk] = (nn < N) ? *(const float4*)(h2 + (size_t)nn * 128 + kk * 4)
                            : make_float4(0.f, 0.f, 0.f, 0.f);
    }
    __syncthreads();

    float acc[8][4];
#pragma unroll
    for (int n = 0; n < 8; ++n)
#pragma unroll
      for (int j = 0; j < 4; ++j) acc[n][j] = 0.f;

#pragma unroll 8
    for (int kk = 0; kk < 32; ++kk) {
      float4 wj[4];
#pragma unroll
      for (int j = 0; j < 4; ++j) wj[j] = w4s[c0 + j][kk ^ m];
#pragma unroll
      for (int n = 0; n < 8; ++n) {
        float4 hv = hs4[grp * 8 + n][kk];
#pragma unroll
        for (int j = 0; j < 4; ++j) {
          acc[n][j] += hv.x * wj[j].x + hv.y * wj[j].y +
                       hv.z * wj[j].z + hv.w * wj[j].w;
        }
      }
    }
#pragma unroll
    for (int n = 0; n < 8; ++n) {
      int nn = n0 + grp * 8 + n;
      if (nn < N)
        *(float4*)(g2 + (size_t)nn * 128 + c0) =
            make_float4(acc[n][0], acc[n][1], acc[n][2], acc[n][3]);
    }

    // fused al2: 32 nodes x 8 (4 src-heads + 4 dst-heads) = 256 dots of 128
    for (int v = 0; v < 2; ++v) {
      int idx = t + 128 * v;
      int n = idx >> 3, j = idx & 7, h = j & 3;
      int nn = n0 + n;
      if (nn < N) {
        const float4* wa = (const float4*)((j < 4 ? wa2s : wa2d) + h * 128);
        float s = 0.f;
#pragma unroll
        for (int kk = 0; kk < 32; ++kk) {
          float4 a = hs4[n][kk];
          float4 w = wa[kk];
          s += a.x * w.x + a.y * w.y + a.z * w.z + a.w * w.w;
        }
        (j < 4 ? al2s : al2d)[(size_t)nn * 4 + h] = s;
      }
    }
  }
}

// ---------------------------------------------------------------------------
// K_pq: per-node fold of decoder layer-1 src/dst blocks.
// pq[n][k]    = sum_c dw1[k][c]    * h3[n][c]   (k<64, c<32)  "P"
// pq[n][64+k] = sum_c dw1[k][32+c] * h3[n][c]                 "Q"
// ---------------------------------------------------------------------------
__global__ void __launch_bounds__(256) k_pq(
    const float* __restrict__ h3, const float* __restrict__ dw1,
    float* __restrict__ pq, int N) {
  __shared__ float4 ws4[64][16];  // dw1 cols 0..63 (P|Q), swizzled slots
  __shared__ float ht[64][32];    // h3 tile
  int t = threadIdx.x;
  for (int i = t; i < 4096; i += 256) {
    int k = i >> 6, c = i & 63;
    ((float*)&ws4[k][(c >> 2) ^ (k & 15)])[c & 3] = dw1[k * 69 + c];
  }
  int n0 = blockIdx.x * 64;
  for (int i = t; i < 2048; i += 256) {
    int n = i >> 5, c = i & 31;
    int nn = n0 + n;
    ht[n][c] = (nn < N) ? h3[(size_t)nn * 32 + c] : 0.f;
  }
  __syncthreads();
  int k2 = t & 127, sub = t >> 7;
  int k = k2 & 63, base4 = (k2 < 64) ? 0 : 8;
  float4 wr[8];
#pragma unroll
  for (int i = 0; i < 8; ++i) wr[i] = ws4[k][(base4 + i) ^ (k & 15)];
  for (int ii = 0; ii < 32; ++ii) {
    int n = sub * 32 + ii;
    const float4* hr = (const float4*)ht[n];
    float s = 0.f;
#pragma unroll
    for (int i = 0; i < 8; ++i) {
      float4 a = hr[i], w = wr[i];
      s += a.x * w.x + a.y * w.y + a.z * w.z + a.w * w.w;
    }
    int nn = n0 + n;
    if (nn < N) pq[(size_t)nn * 128 + k2] = s;
  }
}

// ---------------------------------------------------------------------------
// K_dec: per-edge MLP, CSR (dst-sorted) order. Consecutive threads share d,
// so Q[d] gathers are L1/L2-local; P[s] random; ea/out scattered (small).
//   z1 = relu(P[s] + Q[d] + C*ea + b1); z2 = relu(dw2 z1); out = dw3 z2.
// ---------------------------------------------------------------------------
__global__ void __launch_bounds__(256) k_dec(
    const float* __restrict__ pq, const int* __restrict__ ssrc,
    const int* __restrict__ idst, const int* __restrict__ ieid,
    const float* __restrict__ ea,
    const float* __restrict__ dw1, const float* __restrict__ db1,
    const float* __restrict__ dw2, const float* __restrict__ db2,
    const float* __restrict__ dw3, const float* __restrict__ db3,
    float* __restrict__ out, int E) {
  __shared__ float cs[64][8];   // dw1 cols 64..68, padded
  __shared__ float w2s[32 * 64];
  __shared__ float w3s[4 * 32];
  __shared__ float bbs[104];
  int t = threadIdx.x;
  for (int i = t; i < 512; i += 256) {
    int k = i >> 3, c = i & 7;
    cs[k][c] = (c < 5) ? dw1[k * 69 + 64 + c] : 0.f;
  }
  for (int i = t; i < 2048; i += 256) w2s[i] = dw2[i];
  if (t < 128) w3s[t] = dw3[t];
  if (t < 64) bbs[t] = db1[t];
  else if (t < 96) bbs[t] = db2[t - 64];
  else if (t < 100) bbs[t] = db3[t - 96];
  __syncthreads();

  int pos = blockIdx.x * 256 + t;
  if (pos >= E) return;
  int eid = ieid[pos];
  if (eid < 0) return;  // self-loop slot: conv-only
  int s = ssrc[pos], d = idst[pos];
  const float4* Pp = (const float4*)(pq + (size_t)s * 128);
  const float4* Qp = (const float4*)(pq + (size_t)d * 128 + 64);
  const float* ep = ea + (size_t)eid * 5;
  float e0 = ep[0], e1 = ep[1], e2 = ep[2], e3 = ep[3], e4 = ep[4];

  float z1[64];
#pragma unroll
  for (int i = 0; i < 16; ++i) {
    float4 p = Pp[i], q = Qp[i];
    z1[4 * i + 0] = p.x + q.x;
    z1[4 * i + 1] = p.y + q.y;
    z1[4 * i + 2] = p.z + q.z;
    z1[4 * i + 3] = p.w + q.w;
  }
#pragma unroll
  for (int k = 0; k < 64; ++k) {
    float acc = z1[k] + bbs[k];
    acc += cs[k][0] * e0 + cs[k][1] * e1 + cs[k][2] * e2 + cs[k][3] * e3 +
           cs[k][4] * e4;
    z1[k] = fmaxf(acc, 0.f);
  }

  // layer 2: 64 -> 32
  float z2[32];
#pragma unroll
  for (int k = 0; k < 32; ++k) z2[k] = bbs[64 + k];
#pragma unroll
  for (int cq = 0; cq < 16; ++cq) {
    float4 e = make_float4(z1[cq * 4], z1[cq * 4 + 1], z1[cq * 4 + 2],
                           z1[cq * 4 + 3]);
#pragma unroll
    for (int k = 0; k < 32; ++k) {
      float4 w = *(const float4*)(w2s + k * 64 + cq * 4);
      z2[k] += e.x * w.x + e.y * w.y + e.z * w.z + e.w * w.w;
    }
  }
#pragma unroll
  for (int k = 0; k < 32; ++k) z2[k] = fmaxf(z2[k], 0.f);

  // layer 3: 32 -> 4
  float o0 = bbs[96], o1 = bbs[97], o2 = bbs[98], o3 = bbs[99];
#pragma unroll
  for (int cq = 0; cq < 8; ++cq) {
    float4 e = make_float4(z2[cq * 4], z2[cq * 4 + 1], z2[cq * 4 + 2],
                           z2[cq * 4 + 3]);
    float4 wa = *(const float4*)(w3s + 0 * 32 + cq * 4);
    float4 wb = *(const float4*)(w3s + 1 * 32 + cq * 4);
    float4 wc = *(const float4*)(w3s + 2 * 32 + cq * 4);
    float4 wd = *(const float4*)(w3s + 3 * 32 + cq * 4);
    o0 += e.x * wa.x + e.y * wa.y + e.z * wa.z + e.w * wa.w;
    o1 += e.x * wb.x + e.y * wb.y + e.z * wb.z + e.w * wb.w;
    o2 += e.x * wc.x + e.y * wc.y + e.z * wc.z + e.w * wc.w;
    o3 += e.x * wd.x + e.y * wd.y + e.z * wd.z + e.w * wd.w;
  }
  *(float4*)(out + (size_t)eid * 4) = make_float4(o0, o1, o2, o3);
}

// ---------------------------------------------------------------------------
extern "C" void kernel_launch(void* const* d_in, const int* in_sizes, int n_in,
                              void* d_out, int out_size, void* d_ws, size_t ws_size,
                              hipStream_t stream) {
  const float* x   = (const float*)d_in[0];
  const int*   ei  = (const int*)d_in[1];
  const float* ea  = (const float*)d_in[2];
  const float* u   = (const float*)d_in[3];
  const float* W1  = (const float*)d_in[4];
  const float* as1 = (const float*)d_in[5];
  const float* ad1 = (const float*)d_in[6];
  const float* b1  = (const float*)d_in[7];
  const float* W2  = (const float*)d_in[8];
  const float* as2 = (const float*)d_in[9];
  const float* ad2 = (const float*)d_in[10];
  const float* b2  = (const float*)d_in[11];
  const float* dw1 = (const float*)d_in[12];
  const float* db1 = (const float*)d_in[13];
  const float* dw2 = (const float*)d_in[14];
  const float* db2 = (const float*)d_in[15];
  const float* dw3 = (const float*)d_in[16];
  const float* db3 = (const float*)d_in[17];
  float* out = (float*)d_out;

  const int N = in_sizes[0] / 12;
  const int M = in_sizes[1] / 2;
  const int E = M + N;

  float* ws = (float*)d_ws;
  float* A    = ws;                      // N*128: g1 -> g2 -> PQ
  float* B    = A + (size_t)N * 128;     // N*128: h2, then H3 (first N*32)
  float* H3   = B;                       // alias: h2 dead before k_gat<1> writes
  float* AL1S = B + (size_t)N * 128;     // N*4 each below
  float* AL1D = AL1S + (size_t)N * 4;
  float* AL2S = AL1D + (size_t)N * 4;
  float* AL2D = AL2S + (size_t)N * 4;
  float* WA1S = AL2D + (size_t)N * 4;    // 96 (4x23 padded)
  float* WA1D = WA1S + 96;
  float* WA2S = WA1D + 96;               // 512 (4x128)
  float* WA2D = WA2S + 512;
  // int region
  int* IOFF = (int*)(WA2D + 512);        // N+1
  int* ICUR = IOFF + (N + 1);            // N (counts, then cursors)
  int* IBS  = ICUR + N;                  // 512 block sums
  int* ISRC = IBS + 512;                 // E sorted srcs
  int* IDST = ISRC + E;                  // E sorted dsts
  int* IEID = IDST + E;                  // E orig edge ids (-1 = self-loop)

  int nb = (N + 255) / 256;
  int gE = (E + 255) / 256;

  // --- CSR build (once, reused by both convs + decoder) ---
  k_izero<<<nb, 256, 0, stream>>>(ICUR, N);
  k_count<<<gE, 256, 0, stream>>>(ei, ICUR, M, E);
  k_scan1<<<nb, 256, 0, stream>>>(ICUR, IOFF, IBS, N);
  k_scan2<<<1, 512, 0, stream>>>(IBS, nb);
  k_scan3<<<(N + 256) / 256, 256, 0, stream>>>(IOFF, IBS, ICUR, N, E);
  k_fill<<<gE, 256, 0, stream>>>(ei, IOFF, ICUR, ISRC, IDST, IEID, M, E);

  k_prep<<<1, 512, 0, stream>>>(W1, as1, ad1, W2, as2, ad2, WA1S, WA1D, WA2S, WA2D);

  // --- conv1 ---
  k_g1<<<N, 128, 0, stream>>>(x, u, W1, WA1S, WA1D, A, AL1S, AL1D);
  k_gat<0><<<N, 128, 0, stream>>>(A, AL1S, AL1D, IOFF, ISRC, b1, B);

  // --- conv2 ---
  int ntiles = (N + 31) / 32;
  k_g2t<<<512, 128, 0, stream>>>(B, W2, WA2S, WA2D, A, AL2S, AL2D, N, ntiles);
  k_gat<1><<<N, 128, 0, stream>>>(A, AL2S, AL2D, IOFF, ISRC, b2, H3);

  // --- decoder (A dead -> PQ; CSR order for Q locality) ---
  k_pq<<<(N + 63) / 64, 256, 0, stream>>>(H3, dw1, A, N);
  k_dec<<<gE, 256, 0, stream>>>(A, ISRC, IDST, IEID, ea, dw1, db1, dw2, db2,
                                dw3, db3, out, E);
}

// Round 8
// 1079.688 us; speedup vs baseline: 7.7055x; 1.0389x over previous
//
#include <hip/hip_runtime.h>

#define DEVINL __device__ __forceinline__

DEVINL float leakyf(float v) { return v > 0.f ? v : 0.2f * v; }
DEVINL float eluf(float v)   { return v > 0.f ? v : __expf(v) - 1.f; }

// ---------------------------------------------------------------------------
// int zero fill
// ---------------------------------------------------------------------------
__global__ void __launch_bounds__(256) k_izero(int* __restrict__ p, int total) {
  int t = blockIdx.x * blockDim.x + threadIdx.x;
  if (t < total) p[t] = 0;
}

// ---------------------------------------------------------------------------
// CSR build: count incoming edges per dst (self-loops appended, e >= M).
// ---------------------------------------------------------------------------
__global__ void __launch_bounds__(256) k_count(const int* __restrict__ ei,
                                               int* __restrict__ cnt, int M, int E) {
  int e = blockIdx.x * blockDim.x + threadIdx.x;
  if (e >= E) return;
  int d = (e < M) ? ei[M + e] : e - M;
  atomicAdd(&cnt[d], 1);
}

// Per-256-block exclusive scan; block totals to bsum.
__global__ void __launch_bounds__(256) k_scan1(const int* __restrict__ cnt,
                                               int* __restrict__ off,
                                               int* __restrict__ bsum, int N) {
  __shared__ int sh[256];
  int i = blockIdx.x * 256 + threadIdx.x;
  int v = (i < N) ? cnt[i] : 0;
  sh[threadIdx.x] = v;
  __syncthreads();
  for (int o = 1; o < 256; o <<= 1) {
    int t = (threadIdx.x >= o) ? sh[threadIdx.x - o] : 0;
    __syncthreads();
    sh[threadIdx.x] += t;
    __syncthreads();
  }
  if (i < N) off[i] = sh[threadIdx.x] - v;  // exclusive within block
  if (threadIdx.x == 255) bsum[blockIdx.x] = sh[255];
}

// Exclusive scan of block sums (nb <= 512), one block of 512.
__global__ void __launch_bounds__(512) k_scan2(int* __restrict__ bsum, int nb) {
  __shared__ int sh[512];
  int t = threadIdx.x;
  int v = (t < nb) ? bsum[t] : 0;
  sh[t] = v;
  __syncthreads();
  for (int o = 1; o < 512; o <<= 1) {
    int x = (t >= o) ? sh[t - o] : 0;
    __syncthreads();
    sh[t] += x;
    __syncthreads();
  }
  if (t < nb) bsum[t] = sh[t] - v;
}

// Add block bases; zero cursors; set off[N] = E.
__global__ void __launch_bounds__(256) k_scan3(int* __restrict__ off,
                                               const int* __restrict__ bsum,
                                               int* __restrict__ cur, int N, int E) {
  int i = blockIdx.x * 256 + threadIdx.x;
  if (i < N) { off[i] += bsum[i >> 8]; cur[i] = 0; }
  if (i == N) off[N] = E;
}

// Place (src, dst, orig-edge-id) of each edge into its dst's CSR segment.
__global__ void __launch_bounds__(256) k_fill(const int* __restrict__ ei,
                                              const int* __restrict__ off,
                                              int* __restrict__ cur,
                                              int* __restrict__ ssrc,
                                              int* __restrict__ idst,
                                              int* __restrict__ ieid, int M, int E) {
  int e = blockIdx.x * blockDim.x + threadIdx.x;
  if (e >= E) return;
  int s, d, id;
  if (e < M) { s = ei[e]; d = ei[M + e]; id = e; }
  else       { s = e - M; d = s; id = -1; }
  int pos = off[d] + atomicAdd(&cur[d], 1);
  ssrc[pos] = s;
  idst[pos] = d;
  ieid[pos] = id;
}

// ---------------------------------------------------------------------------
// K_prep: fold attention vectors into input space.
// ---------------------------------------------------------------------------
__global__ void k_prep(const float* __restrict__ W1, const float* __restrict__ as1,
                       const float* __restrict__ ad1,
                       const float* __restrict__ W2, const float* __restrict__ as2,
                       const float* __restrict__ ad2,
                       float* __restrict__ wa1s, float* __restrict__ wa1d,
                       float* __restrict__ wa2s, float* __restrict__ wa2d) {
  int t = threadIdx.x;  // 512 threads
  if (t < 92) {
    int h = t / 23, c = t % 23;
    float s1 = 0.f, s2 = 0.f;
    for (int dd = 0; dd < 32; ++dd) {
      float w = W1[(h * 32 + dd) * 23 + c];
      s1 += w * as1[h * 32 + dd];
      s2 += w * ad1[h * 32 + dd];
    }
    wa1s[t] = s1;
    wa1d[t] = s2;
  }
  {
    int h = t >> 7, c = t & 127;
    float s1 = 0.f, s2 = 0.f;
    for (int dd = 0; dd < 32; ++dd) {
      float w = W2[(h * 32 + dd) * 128 + c];
      s1 += w * as2[h * 32 + dd];
      s2 += w * ad2[h * 32 + dd];
    }
    wa2s[t] = s1;
    wa2d[t] = s2;
  }
}

// ---------------------------------------------------------------------------
// K_g1: g1[n,k] = h_n . W1[k,:], plus folded attention logits.
// ---------------------------------------------------------------------------
__global__ void __launch_bounds__(128) k_g1(
    const float* __restrict__ x, const float* __restrict__ u,
    const float* __restrict__ W1,
    const float* __restrict__ wa1s, const float* __restrict__ wa1d,
    float* __restrict__ g1, float* __restrict__ al1s, float* __restrict__ al1d) {
  int n = blockIdx.x, k = threadIdx.x;
  __shared__ float hs[23];
  if (k < 12) hs[k] = x[n * 12 + k];
  else if (k < 23) hs[k] = u[k - 12];
  __syncthreads();
  const float* w = W1 + k * 23;
  float s = 0.f;
#pragma unroll
  for (int c = 0; c < 23; ++c) s += hs[c] * w[c];
  g1[n * 128 + k] = s;
  if (k < 8) {
    int h = k & 3;
    const float* wa = (k < 4 ? wa1s : wa1d) + h * 23;
    float t = 0.f;
#pragma unroll
    for (int c = 0; c < 23; ++c) t += hs[c] * wa[c];
    (k < 4 ? al1s : al1d)[n * 4 + h] = t;
  }
}

// ---------------------------------------------------------------------------
// K_gat: fused attention + softmax + aggregate per dst node via CSR gather.
// One WAVE per node (lane covers 2 channels via float2); 4 nodes per block.
// No LDS, no syncthreads; CSR walk is wave-uniform (scalar loads).
// MODE 1 head-mean via shfl_xor(16)+shfl_xor(32).
// ---------------------------------------------------------------------------
template <int MODE>
__global__ void __launch_bounds__(256) k_gat(
    const float* __restrict__ g, const float* __restrict__ als,
    const float* __restrict__ ald, const int* __restrict__ off,
    const int* __restrict__ ssrc, const float* __restrict__ bias,
    float* __restrict__ outp, int N) {
  int wid = threadIdx.x >> 6, lane = threadIdx.x & 63;
  int d = blockIdx.x * 4 + wid;
  if (d >= N) return;
  int h = lane >> 4;  // 16 lanes per head, 32 channels per head
  float av = ald[d * 4 + h];
  int p0 = off[d], p1 = off[d + 1];
  float accx = 0.f, accy = 0.f, den = 0.f;
  int p = p0;
  for (; p + 4 <= p1; p += 4) {
    int s0 = ssrc[p], s1 = ssrc[p + 1], s2 = ssrc[p + 2], s3 = ssrc[p + 3];
    float l0 = als[s0 * 4 + h], l1 = als[s1 * 4 + h];
    float l2 = als[s2 * 4 + h], l3 = als[s3 * 4 + h];
    float2 G0 = *(const float2*)(g + (size_t)s0 * 128 + 2 * lane);
    float2 G1 = *(const float2*)(g + (size_t)s1 * 128 + 2 * lane);
    float2 G2 = *(const float2*)(g + (size_t)s2 * 128 + 2 * lane);
    float2 G3 = *(const float2*)(g + (size_t)s3 * 128 + 2 * lane);
    float w0 = __expf(leakyf(l0 + av)), w1 = __expf(leakyf(l1 + av));
    float w2 = __expf(leakyf(l2 + av)), w3 = __expf(leakyf(l3 + av));
    accx += w0 * G0.x + w1 * G1.x + w2 * G2.x + w3 * G3.x;
    accy += w0 * G0.y + w1 * G1.y + w2 * G2.y + w3 * G3.y;
    den += (w0 + w1) + (w2 + w3);
  }
  for (; p < p1; ++p) {
    int s = ssrc[p];
    float w = __expf(leakyf(als[s * 4 + h] + av));
    float2 G = *(const float2*)(g + (size_t)s * 128 + 2 * lane);
    accx += w * G.x;
    accy += w * G.y;
    den += w;
  }
  float inv = 1.f / den;
  float vx = accx * inv, vy = accy * inv;
  if (MODE == 0) {
    float2 b = *(const float2*)(bias + 2 * lane);
    float2 o;
    o.x = eluf(vx + b.x);
    o.y = eluf(vy + b.y);
    *(float2*)(outp + (size_t)d * 128 + 2 * lane) = o;
  } else {
    // mean over 4 heads: lanes {m, m+16, m+32, m+48} hold same channel pair
    float sx = vx + __shfl_xor(vx, 16);
    sx += __shfl_xor(sx, 32);
    float sy = vy + __shfl_xor(vy, 16);
    sy += __shfl_xor(sy, 32);
    if (lane < 16) {
      float2 o;
      o.x = eluf(0.25f * sx + bias[2 * lane]);
      o.y = eluf(0.25f * sy + bias[2 * lane + 1]);
      *(float2*)(outp + (size_t)d * 32 + 2 * lane) = o;
    }
  }
}

// ---------------------------------------------------------------------------
// K_g2t: LDS-tiled GEMM  g2[n,c] = sum_k h2[n,k] * W2[c,k]  (+ fused al2).
// ---------------------------------------------------------------------------
__global__ void __launch_bounds__(128) k_g2t(
    const float* __restrict__ h2, const float* __restrict__ W2,
    const float* __restrict__ wa2s, const float* __restrict__ wa2d,
    float* __restrict__ g2, float* __restrict__ al2s, float* __restrict__ al2d,
    int N, int ntiles) {
  __shared__ float4 w4s[128][32];  // 64 KB, [c][slot]
  __shared__ float4 hs4[32][32];   // 16 KB, [node][k4]
  int t = threadIdx.x;

  // stage W2 with swizzle: w4s[c][kk ^ ((c>>2)&31)] = W2[c][4kk..4kk+3]
  for (int i = t; i < 4096; i += 128) {
    int c = i >> 5, kk = i & 31;
    float4 v = *(const float4*)(W2 + c * 128 + kk * 4);
    w4s[c][kk ^ ((c >> 2) & 31)] = v;
  }

  int m = t & 31, grp = t >> 5;
  int c0 = 4 * m;

  for (int tile = blockIdx.x; tile < ntiles; tile += gridDim.x) {
    int n0 = tile * 32;
    __syncthreads();  // prev-tile readers done before overwrite (also covers W2 stage)
    for (int i = t; i < 1024; i += 128) {
      int n = i >> 5, kk = i & 31;
      int nn = n0 + n;
      hs4[n][kk] = (nn < N) ? *(const float4*)(h2 + (size_t)nn * 128 + kk * 4)
                            : make_float4(0.f, 0.f, 0.f, 0.f);
    }
    __syncthreads();

    float acc[8][4];
#pragma unroll
    for (int n = 0; n < 8; ++n)
#pragma unroll
      for (int j = 0; j < 4; ++j) acc[n][j] = 0.f;

#pragma unroll 8
    for (int kk = 0; kk < 32; ++kk) {
      float4 wj[4];
#pragma unroll
      for (int j = 0; j < 4; ++j) wj[j] = w4s[c0 + j][kk ^ m];
#pragma unroll
      for (int n = 0; n < 8; ++n) {
        float4 hv = hs4[grp * 8 + n][kk];
#pragma unroll
        for (int j = 0; j < 4; ++j) {
          acc[n][j] += hv.x * wj[j].x + hv.y * wj[j].y +
                       hv.z * wj[j].z + hv.w * wj[j].w;
        }
      }
    }
#pragma unroll
    for (int n = 0; n < 8; ++n) {
      int nn = n0 + grp * 8 + n;
      if (nn < N)
        *(float4*)(g2 + (size_t)nn * 128 + c0) =
            make_float4(acc[n][0], acc[n][1], acc[n][2], acc[n][3]);
    }

    // fused al2: 32 nodes x 8 (4 src-heads + 4 dst-heads) = 256 dots of 128
    for (int v = 0; v < 2; ++v) {
      int idx = t + 128 * v;
      int n = idx >> 3, j = idx & 7, h = j & 3;
      int nn = n0 + n;
      if (nn < N) {
        const float4* wa = (const float4*)((j < 4 ? wa2s : wa2d) + h * 128);
        float s = 0.f;
#pragma unroll
        for (int kk = 0; kk < 32; ++kk) {
          float4 a = hs4[n][kk];
          float4 w = wa[kk];
          s += a.x * w.x + a.y * w.y + a.z * w.z + a.w * w.w;
        }
        (j < 4 ? al2s : al2d)[(size_t)nn * 4 + h] = s;
      }
    }
  }
}

// ---------------------------------------------------------------------------
// K_pq: per-node fold of decoder layer-1 src/dst blocks.
// pq[n][k]    = sum_c dw1[k][c]    * h3[n][c]   (k<64, c<32)  "P"
// pq[n][64+k] = sum_c dw1[k][32+c] * h3[n][c]                 "Q"
// ---------------------------------------------------------------------------
__global__ void __launch_bounds__(256) k_pq(
    const float* __restrict__ h3, const float* __restrict__ dw1,
    float* __restrict__ pq, int N) {
  __shared__ float4 ws4[64][16];  // dw1 cols 0..63 (P|Q), swizzled slots
  __shared__ float ht[64][32];    // h3 tile
  int t = threadIdx.x;
  for (int i = t; i < 4096; i += 256) {
    int k = i >> 6, c = i & 63;
    ((float*)&ws4[k][(c >> 2) ^ (k & 15)])[c & 3] = dw1[k * 69 + c];
  }
  int n0 = blockIdx.x * 64;
  for (int i = t; i < 2048; i += 256) {
    int n = i >> 5, c = i & 31;
    int nn = n0 + n;
    ht[n][c] = (nn < N) ? h3[(size_t)nn * 32 + c] : 0.f;
  }
  __syncthreads();
  int k2 = t & 127, sub = t >> 7;
  int k = k2 & 63, base4 = (k2 < 64) ? 0 : 8;
  float4 wr[8];
#pragma unroll
  for (int i = 0; i < 8; ++i) wr[i] = ws4[k][(base4 + i) ^ (k & 15)];
  for (int ii = 0; ii < 32; ++ii) {
    int n = sub * 32 + ii;
    const float4* hr = (const float4*)ht[n];
    float s = 0.f;
#pragma unroll
    for (int i = 0; i < 8; ++i) {
      float4 a = hr[i], w = wr[i];
      s += a.x * w.x + a.y * w.y + a.z * w.z + a.w * w.w;
    }
    int nn = n0 + n;
    if (nn < N) pq[(size_t)nn * 128 + k2] = s;
  }
}

// ---------------------------------------------------------------------------
// K_dec: per-edge MLP, CSR order, TWO edges per thread, z1 streamed by quads
// (never materialized): every LDS weight read is shared by both edges.
//   z1q = relu(P[s]q + Q[d]q + Ct.q*ea + b1q); z2 += w2q . z1q ; out = w3 z2.
// ---------------------------------------------------------------------------
__global__ void __launch_bounds__(256) k_dec(
    const float* __restrict__ pq, const int* __restrict__ ssrc,
    const int* __restrict__ idst, const int* __restrict__ ieid,
    const float* __restrict__ ea,
    const float* __restrict__ dw1, const float* __restrict__ db1,
    const float* __restrict__ dw2, const float* __restrict__ db2,
    const float* __restrict__ dw3, const float* __restrict__ db3,
    float* __restrict__ out, int E) {
  __shared__ float4 w2s4[32][16];  // [k][cq] = dw2[k][4cq..]
  __shared__ float4 ct4[5][16];    // [c][cq].j = dw1[(4cq+j)*69 + 64 + c]
  __shared__ float4 b1q[16];       // db1 quads
  __shared__ float4 b2q[8];        // db2 quads
  __shared__ float4 w3s4[4][8];    // [o][cq2].j = dw3[o*32 + 4cq2 + j]
  __shared__ float  db3s[4];
  int t = threadIdx.x;
  for (int i = t; i < 512; i += 256) {
    int k = i >> 4, cq = i & 15;
    w2s4[k][cq] = *(const float4*)(dw2 + k * 64 + cq * 4);
  }
  if (t < 80) {
    int c = t / 16, cq = t % 16;
    float4 v;
    v.x = dw1[(4 * cq + 0) * 69 + 64 + c];
    v.y = dw1[(4 * cq + 1) * 69 + 64 + c];
    v.z = dw1[(4 * cq + 2) * 69 + 64 + c];
    v.w = dw1[(4 * cq + 3) * 69 + 64 + c];
    ct4[c][cq] = v;
  } else if (t < 96) {
    b1q[t - 80] = *(const float4*)(db1 + 4 * (t - 80));
  } else if (t < 104) {
    b2q[t - 96] = *(const float4*)(db2 + 4 * (t - 96));
  } else if (t < 136) {
    int o = (t - 104) >> 3, cq = (t - 104) & 7;
    w3s4[o][cq] = *(const float4*)(dw3 + o * 32 + 4 * cq);
  } else if (t < 140) {
    db3s[t - 136] = db3[t - 136];
  }
  __syncthreads();

  int pos0 = blockIdx.x * 512 + t;
  int pos1 = pos0 + 256;
  bool okA = pos0 < E, okB = pos1 < E;
  int pa = okA ? pos0 : 0, pb = okB ? pos1 : 0;
  int eA_ = okA ? ieid[pa] : -1;
  int eB_ = okB ? ieid[pb] : -1;
  bool wA = eA_ >= 0, wB = eB_ >= 0;
  int eidA = wA ? eA_ : 0, eidB = wB ? eB_ : 0;
  int sA = ssrc[pa], dA = idst[pa];
  int sB = ssrc[pb], dB = idst[pb];
  const float4* PA = (const float4*)(pq + (size_t)sA * 128);
  const float4* QA = (const float4*)(pq + (size_t)dA * 128 + 64);
  const float4* PB = (const float4*)(pq + (size_t)sB * 128);
  const float4* QB = (const float4*)(pq + (size_t)dB * 128 + 64);
  const float* eap = ea + (size_t)eidA * 5;
  const float* ebp = ea + (size_t)eidB * 5;
  float eAv[5], eBv[5];
#pragma unroll
  for (int c = 0; c < 5; ++c) { eAv[c] = eap[c]; eBv[c] = ebp[c]; }

  float z2a[32], z2b[32];
#pragma unroll
  for (int kq = 0; kq < 8; ++kq) {
    float4 b = b2q[kq];
    z2a[4 * kq + 0] = b.x; z2a[4 * kq + 1] = b.y;
    z2a[4 * kq + 2] = b.z; z2a[4 * kq + 3] = b.w;
    z2b[4 * kq + 0] = b.x; z2b[4 * kq + 1] = b.y;
    z2b[4 * kq + 2] = b.z; z2b[4 * kq + 3] = b.w;
  }

  for (int cq = 0; cq < 16; ++cq) {
    float4 pA = PA[cq], qA = QA[cq];
    float4 pB = PB[cq], qB = QB[cq];
    float4 bq = b1q[cq];
    float4 zA, zB;
    zA.x = pA.x + qA.x + bq.x; zA.y = pA.y + qA.y + bq.y;
    zA.z = pA.z + qA.z + bq.z; zA.w = pA.w + qA.w + bq.w;
    zB.x = pB.x + qB.x + bq.x; zB.y = pB.y + qB.y + bq.y;
    zB.z = pB.z + qB.z + bq.z; zB.w = pB.w + qB.w + bq.w;
#pragma unroll
    for (int c = 0; c < 5; ++c) {
      float4 cc = ct4[c][cq];
      float ca = eAv[c], cb = eBv[c];
      zA.x += ca * cc.x; zA.y += ca * cc.y; zA.z += ca * cc.z; zA.w += ca * cc.w;
      zB.x += cb * cc.x; zB.y += cb * cc.y; zB.z += cb * cc.z; zB.w += cb * cc.w;
    }
    zA.x = fmaxf(zA.x, 0.f); zA.y = fmaxf(zA.y, 0.f);
    zA.z = fmaxf(zA.z, 0.f); zA.w = fmaxf(zA.w, 0.f);
    zB.x = fmaxf(zB.x, 0.f); zB.y = fmaxf(zB.y, 0.f);
    zB.z = fmaxf(zB.z, 0.f); zB.w = fmaxf(zB.w, 0.f);
#pragma unroll
    for (int k = 0; k < 32; ++k) {
      float4 w = w2s4[k][cq];
      z2a[k] += w.x * zA.x + w.y * zA.y + w.z * zA.z + w.w * zA.w;
      z2b[k] += w.x * zB.x + w.y * zB.y + w.z * zB.z + w.w * zB.w;
    }
  }
#pragma unroll
  for (int k = 0; k < 32; ++k) {
    z2a[k] = fmaxf(z2a[k], 0.f);
    z2b[k] = fmaxf(z2b[k], 0.f);
  }

  float oA[4], oB[4];
#pragma unroll
  for (int o = 0; o < 4; ++o) { oA[o] = db3s[o]; oB[o] = db3s[o]; }
#pragma unroll
  for (int cq = 0; cq < 8; ++cq) {
    float ax = z2a[4 * cq], ay = z2a[4 * cq + 1];
    float az = z2a[4 * cq + 2], aw = z2a[4 * cq + 3];
    float bx = z2b[4 * cq], by = z2b[4 * cq + 1];
    float bz = z2b[4 * cq + 2], bw = z2b[4 * cq + 3];
#pragma unroll
    for (int o = 0; o < 4; ++o) {
      float4 w = w3s4[o][cq];
      oA[o] += ax * w.x + ay * w.y + az * w.z + aw * w.w;
      oB[o] += bx * w.x + by * w.y + bz * w.z + bw * w.w;
    }
  }
  if (wA && okA)
    *(float4*)(out + (size_t)eidA * 4) = make_float4(oA[0], oA[1], oA[2], oA[3]);
  if (wB && okB)
    *(float4*)(out + (size_t)eidB * 4) = make_float4(oB[0], oB[1], oB[2], oB[3]);
}

// ---------------------------------------------------------------------------
extern "C" void kernel_launch(void* const* d_in, const int* in_sizes, int n_in,
                              void* d_out, int out_size, void* d_ws, size_t ws_size,
                              hipStream_t stream) {
  const float* x   = (const float*)d_in[0];
  const int*   ei  = (const int*)d_in[1];
  const float* ea  = (const float*)d_in[2];
  const float* u   = (const float*)d_in[3];
  const float* W1  = (const float*)d_in[4];
  const float* as1 = (const float*)d_in[5];
  const float* ad1 = (const float*)d_in[6];
  const float* b1  = (const float*)d_in[7];
  const float* W2  = (const float*)d_in[8];
  const float* as2 = (const float*)d_in[9];
  const float* ad2 = (const float*)d_in[10];
  const float* b2  = (const float*)d_in[11];
  const float* dw1 = (const float*)d_in[12];
  const float* db1 = (const float*)d_in[13];
  const float* dw2 = (const float*)d_in[14];
  const float* db2 = (const float*)d_in[15];
  const float* dw3 = (const float*)d_in[16];
  const float* db3 = (const float*)d_in[17];
  float* out = (float*)d_out;

  const int N = in_sizes[0] / 12;
  const int M = in_sizes[1] / 2;
  const int E = M + N;

  float* ws = (float*)d_ws;
  float* A    = ws;                      // N*128: g1 -> g2 -> PQ
  float* B    = A + (size_t)N * 128;     // N*128: h2, then H3 (first N*32)
  float* H3   = B;                       // alias: h2 dead before k_gat<1> writes
  float* AL1S = B + (size_t)N * 128;     // N*4 each below
  float* AL1D = AL1S + (size_t)N * 4;
  float* AL2S = AL1D + (size_t)N * 4;
  float* AL2D = AL2S + (size_t)N * 4;
  float* WA1S = AL2D + (size_t)N * 4;    // 96 (4x23 padded)
  float* WA1D = WA1S + 96;
  float* WA2S = WA1D + 96;               // 512 (4x128)
  float* WA2D = WA2S + 512;
  // int region
  int* IOFF = (int*)(WA2D + 512);        // N+1
  int* ICUR = IOFF + (N + 1);            // N (counts, then cursors)
  int* IBS  = ICUR + N;                  // 512 block sums
  int* ISRC = IBS + 512;                 // E sorted srcs
  int* IDST = ISRC + E;                  // E sorted dsts
  int* IEID = IDST + E;                  // E orig edge ids (-1 = self-loop)

  int nb = (N + 255) / 256;
  int gE = (E + 255) / 256;

  // --- CSR build (once, reused by both convs + decoder) ---
  k_izero<<<nb, 256, 0, stream>>>(ICUR, N);
  k_count<<<gE, 256, 0, stream>>>(ei, ICUR, M, E);
  k_scan1<<<nb, 256, 0, stream>>>(ICUR, IOFF, IBS, N);
  k_scan2<<<1, 512, 0, stream>>>(IBS, nb);
  k_scan3<<<(N + 256) / 256, 256, 0, stream>>>(IOFF, IBS, ICUR, N, E);
  k_fill<<<gE, 256, 0, stream>>>(ei, IOFF, ICUR, ISRC, IDST, IEID, M, E);

  k_prep<<<1, 512, 0, stream>>>(W1, as1, ad1, W2, as2, ad2, WA1S, WA1D, WA2S, WA2D);

  // --- conv1 ---
  k_g1<<<N, 128, 0, stream>>>(x, u, W1, WA1S, WA1D, A, AL1S, AL1D);
  k_gat<0><<<(N + 3) / 4, 256, 0, stream>>>(A, AL1S, AL1D, IOFF, ISRC, b1, B, N);

  // --- conv2 ---
  int ntiles = (N + 31) / 32;
  k_g2t<<<512, 128, 0, stream>>>(B, W2, WA2S, WA2D, A, AL2S, AL2D, N, ntiles);
  k_gat<1><<<(N + 3) / 4, 256, 0, stream>>>(A, AL2S, AL2D, IOFF, ISRC, b2, H3, N);

  // --- decoder (A dead -> PQ; CSR order for Q locality) ---
  k_pq<<<(N + 63) / 64, 256, 0, stream>>>(H3, dw1, A, N);
  k_dec<<<(E + 511) / 512, 256, 0, stream>>>(A, ISRC, IDST, IEID, ea, dw1, db1,
                                             dw2, db2, dw3, db3, out, E);
}